// Round 2
// baseline (10103.243 us; speedup 1.0000x reference)
//
#include <hip/hip_runtime.h>
#include <hip/hip_bf16.h>

#define VV 50000
#define DD 256
#define HH 128
#define G4 512
#define BB 8
#define SS 512
#define TT 100
#define T1 101
#define GAMMA 1.0f
#define LOG2E 1.44269504f
#define NTILES 3136          // 196 blocks * 16 tiles of 16 vocab (>= 3125)
#define CBLK 196

__device__ inline float rcpf_(float x){
#if __has_builtin(__builtin_amdgcn_rcpf)
  return __builtin_amdgcn_rcpf(x);
#else
  return 1.0f/x;
#endif
}
__device__ inline float exp2f_(float x){
#if __has_builtin(__builtin_amdgcn_exp2f)
  return __builtin_amdgcn_exp2f(x);
#else
  return exp2f(x);
#endif
}
__device__ inline float log2f_(float x){
#if __has_builtin(__builtin_amdgcn_logf)
  return __builtin_amdgcn_logf(x);
#else
  return log2f(x);
#endif
}
__device__ inline float fexp(float x){ return exp2f_(x*LOG2E); }
__device__ inline float sigf(float x){ return rcpf_(1.f + fexp(-x)); }
__device__ inline float tanh_(float x){
  x = fminf(12.f, fmaxf(-12.f, x));
  float e = fexp(2.f*x);
  return (e-1.f)*rcpf_(e+1.f);
}
__device__ inline unsigned short f2bf(float x){
  unsigned u = __float_as_uint(x);
  return (unsigned short)((u + 0x7fffu + ((u>>16)&1u)) >> 16);
}
__device__ inline unsigned pack2(float a, float b){ return (unsigned)f2bf(a) | ((unsigned)f2bf(b)<<16); }
__device__ inline float bf2f(unsigned short s){ return __uint_as_float(((unsigned)s)<<16); }

typedef __attribute__((ext_vector_type(2))) _Float16 h2v;
typedef __attribute__((ext_vector_type(8))) short bfrag;
typedef __attribute__((ext_vector_type(4))) float cfrag;

__device__ inline unsigned packh2(float a, float b){
  unsigned short ha = __builtin_bit_cast(unsigned short, (_Float16)a);
  unsigned short hb = __builtin_bit_cast(unsigned short, (_Float16)b);
  return (unsigned)ha | ((unsigned)hb<<16);
}
__device__ inline float fdot2_(unsigned a, unsigned b, float c){
#if __has_builtin(__builtin_amdgcn_fdot2)
  return __builtin_amdgcn_fdot2(__builtin_bit_cast(h2v, a), __builtin_bit_cast(h2v, b), c, false);
#else
  h2v av = __builtin_bit_cast(h2v, a), bv = __builtin_bit_cast(h2v, b);
  return c + (float)av.x*(float)bv.x + (float)av.y*(float)bv.y;
#endif
}

// ---------------- prep: small weight transposes/packs ----------------
__global__ void __launch_bounds__(256) k_prep_small(
    const float* Wih_f, const float* Wih_b, const float* Whh_f, const float* Whh_b,
    const float* W1, const float* W2,
    float* WihT_f, float* WihT_b, unsigned* W2T_f, unsigned* W2T_b,
    float* W1hT, float* W1aT, float* W1c){
  int i = blockIdx.x*256 + threadIdx.x;
  if (i < 131072){ int k = i>>9, j = i&511; WihT_f[i] = Wih_f[j*DD + k]; return; }
  i -= 131072;
  if (i < 131072){ int k = i>>9, j = i&511; WihT_b[i] = Wih_b[j*DD + k]; return; }
  i -= 131072;
  if (i < 32768){ int k2 = i>>9, j = i&511;
    W2T_f[i] = packh2(Whh_f[j*HH + 2*k2], Whh_f[j*HH + 2*k2+1]); return; }
  i -= 32768;
  if (i < 32768){ int k2 = i>>9, j = i&511;
    W2T_b[i] = packh2(Whh_b[j*HH + 2*k2], Whh_b[j*HH + 2*k2+1]); return; }
  i -= 32768;
  if (i < 16384){ int j = i>>7, k = i&127; W1hT[i] = W1[k*385 + 256 + j]; return; }
  i -= 16384;
  if (i < 32768){ int d = i>>7, k = i&127; W1aT[i] = W1[k*385 + d]; return; }
  i -= 32768;
  if (i < 128){ W1c[i] = W1[i*385 + 384]; return; }
}

// ---------------- prep: Wl -> bf16 MFMA B-fragment layout ----------------
// element f = (ntile*12 + ks)*64 + lane ; n = ntile*16 + (lane&15) ;
// k = ks*32 + (lane>>4)*8 + j (j = short index inside uint4)
__global__ void __launch_bounds__(256) k_prep_wlB(const float* Wl, uint4* WlB){
  int f = blockIdx.x*256 + threadIdx.x;
  int lane = f & 63;
  int g = f >> 6;
  int ks = g % 12;
  int ntile = g / 12;
  int n = ntile*16 + (lane & 15);
  int k = ks*32 + (lane >> 4)*8;
  uint4 o = make_uint4(0,0,0,0);
  if (n < VV){
    const float* p = Wl + (size_t)n*384 + k;
    float4 w0 = ((const float4*)p)[0];
    float4 w1 = ((const float4*)p)[1];
    o.x = pack2(w0.x, w0.y); o.y = pack2(w0.z, w0.w);
    o.z = pack2(w1.x, w1.y); o.w = pack2(w1.z, w1.w);
  }
  WlB[f] = o;
}

// ---------------- embedding gather + ridx ----------------
__global__ void k_embed(const int* text, const int* tlen, const float* wv,
                        float* emb, int* ridx){
  int blk = blockIdx.x;            // b*512+s
  int b = blk>>9, s = blk&511;
  int tok = text[blk];
  const float4* src = (const float4*)(wv + (size_t)tok*DD);
  float4* dst = (float4*)(emb + (size_t)blk*DD);
  dst[threadIdx.x] = src[threadIdx.x];
  if (threadIdx.x==0){ int len = tlen[b]; ridx[blk] = (s < len) ? (len-1-s) : s; }
}

// ---------------- X = emb @ Wih^T + bih + bhh ----------------
__global__ void __launch_bounds__(256) k_xgemm(const float* emb, const int* ridx,
    const float* WihT, const float* bi, const float* bh, float* X, int rev){
  __shared__ float e_l[8][256];
  int tid = threadIdx.x;
  int g0 = blockIdx.x*8;
  int b = g0>>9;
  for (int r=0;r<8;r++){
    int s = (g0+r)&511;
    int src = rev ? ridx[b*SS + s] : s;
    e_l[r][tid] = emb[((size_t)(b*SS+src))*DD + tid];
  }
  __syncthreads();
  int j0 = tid, j1 = tid+256;
  float acc0[8], acc1[8];
  #pragma unroll
  for (int r=0;r<8;r++){ acc0[r]=0.f; acc1[r]=0.f; }
  for (int k=0;k<256;k++){
    float w0 = WihT[k*G4 + j0];
    float w1 = WihT[k*G4 + j1];
    #pragma unroll
    for (int r=0;r<8;r++){ float e = e_l[r][k]; acc0[r] += e*w0; acc1[r] += e*w1; }
  }
  float bb0 = bi[j0]+bh[j0], bb1 = bi[j1]+bh[j1];
  for (int r=0;r<8;r++){
    X[((size_t)(g0+r))*G4 + j0] = acc0[r] + bb0;
    X[((size_t)(g0+r))*G4 + j1] = acc1[r] + bb1;
  }
}

// ---------------- encoder: register-resident Whh (f16 pairs) ----------------
__global__ void __launch_bounds__(512) k_encoder(const float* Xf, const float* Xb,
    const unsigned* W2Tf, const unsigned* W2Tb, const int* tlen,
    float* out_f, float* out_r, float* h0, float* c0){
  __shared__ float g_l[512];
  __shared__ __align__(16) unsigned h2_l[64];   // 128 f16 of h
  int tid = threadIdx.x;
  int b = blockIdx.x, dir = blockIdx.y;
  const float* X = dir ? Xb : Xf;
  const unsigned* WT = dir ? W2Tb : W2Tf;
  float* out = dir ? out_r : out_f;
  unsigned w[64];
  #pragma unroll
  for (int k2=0;k2<64;k2++) w[k2] = WT[k2*G4 + tid];
  if (tid < 64) h2_l[tid] = 0u;
  float creg = 0.f;
  int len = tlen[b];
  float xx = X[(size_t)(b*SS)*G4 + tid];
  __syncthreads();
  for (int t=0;t<len;t++){
    float acc = xx;
    const uint4* h4 = (const uint4*)h2_l;
    #pragma unroll
    for (int q=0;q<16;q++){
      uint4 hv = h4[q];
      acc = fdot2_(w[4*q+0], hv.x, acc);
      acc = fdot2_(w[4*q+1], hv.y, acc);
      acc = fdot2_(w[4*q+2], hv.z, acc);
      acc = fdot2_(w[4*q+3], hv.w, acc);
    }
    xx = X[(size_t)(b*SS+t+1)*G4 + tid];   // prefetch (buffer padded by G4)
    g_l[tid] = acc;
    __syncthreads();
    if (tid < 128){
      float ii = sigf(g_l[tid]);
      float ff = sigf(g_l[128+tid]);
      float gg = tanh_(g_l[256+tid]);
      float oo = sigf(g_l[384+tid]);
      creg = ff*creg + ii*gg;
      float hn = oo*tanh_(creg);
      out[((size_t)(b*SS+t))*HH + tid] = hn;
      ((_Float16*)h2_l)[tid] = (_Float16)hn;
      if (dir==0 && t==len-1){ h0[b*HH+tid]=hn; c0[b*HH+tid]=creg; }
    }
    __syncthreads();
  }
  for (int f = tid; f < (SS-len)*HH; f += 512){
    int s = len + (f>>7), j = f&127;
    out[((size_t)(b*SS+s))*HH + j] = 0.f;
  }
}

// ---------------- post-encoder: ts_bf16 + TS1T ----------------
__global__ void __launch_bounds__(256) k_post(const float* out_f, const float* out_r,
    const int* ridx, const float* W1aT, unsigned short* ts_bf, float* TS1T){
  __shared__ float ts_l[32*256];
  int tid = threadIdx.x;
  int b = blockIdx.x, chunk = blockIdx.y;
  int s0 = chunk*32;
  for (int it=0; it<32; ++it){
    int s = s0 + it;
    int d = tid;
    float v;
    if (d < 128) v = out_f[((size_t)(b*SS+s))*HH + d];
    else        v = out_r[((size_t)(b*SS + ridx[b*SS+s]))*HH + (d-128)];
    ts_l[it*256 + d] = v;
    ts_bf[((size_t)(b*SS+s))*256 + d] = f2bf(v);
  }
  __syncthreads();
  int k = tid & 127, half = tid >> 7;
  float acc[16];
  #pragma unroll
  for (int i=0;i<16;i++) acc[i]=0.f;
  for (int d=0;d<256;d++){
    float w = W1aT[d*128 + k];
    #pragma unroll
    for (int i=0;i<16;i++) acc[i] += ts_l[(half*16+i)*256 + d]*w;
  }
  for (int i=0;i<16;i++){
    int s = s0 + half*16 + i;
    TS1T[((size_t)(b*128+k))*SS + s] = acc[i];
  }
}

// ---------------- decoder state init ----------------
__global__ void k_init(const float* h0, const float* c0, float* h, float* c,
                       float* cov, float* loss){
  int b = blockIdx.x, tid = threadIdx.x;
  if (tid<128){ h[b*HH+tid]=h0[b*HH+tid]; c[b*HH+tid]=c0[b*HH+tid]; }
  cov[b*SS + tid] = 0.f; cov[b*SS + 256 + tid] = 0.f;
  if (b==0 && tid==0) loss[0]=0.f;
}

// ---------------- combine: LSE + loss accumulate (call with all threads) -----
__device__ void dec_combine(int tc, int nblk, const float* pm, const float* ps,
                            const float* tgt, const float* covloss,
                            const int* slen, float* loss, float* red){
  int tid = threadIdx.x;
  if (tid < 256){
    int b = tid >> 5, i = tid & 31;
    float m = -1e30f;
    for (int jb=i; jb<nblk; jb+=32) m = fmaxf(m, pm[jb*BB + b]);
    #pragma unroll
    for (int off=16;off>=1;off>>=1) m = fmaxf(m, __shfl_xor(m, off, 64));
    float s = 0.f;
    for (int jb=i; jb<nblk; jb+=32) s += ps[jb*BB + b]*fexp(pm[jb*BB+b]-m);
    #pragma unroll
    for (int off=16;off>=1;off>>=1) s += __shfl_xor(s, off, 64);
    if (i==0){
      float lse = m + log2f_(s)*0.6931472f;
      bool val = slen[b] > tc+1;
      red[b] = val ? (lse - tgt[b] + GAMMA*covloss[b]) : 0.f;
    }
  }
  __syncthreads();
  if (tid==0){
    float sum=0.f;
    #pragma unroll
    for (int b2=0;b2<BB;b2++) sum += red[b2];
    loss[0] += sum;
  }
}

// ---------------- stepC (MFMA vocab GEMM) ----------------
struct C2Args {
  const int* summary; const float* wv; const float* Wdih; const float* Wdhh;
  const float* bdih; const float* bdhh; const float* h; const float* hn;
  const float* context; const short* WlB; const float* bl;
  float* gates; float* pm; float* ps; float* tgt; int t;
};

__global__ void __launch_bounds__(256) k_stepC(C2Args a){
  __shared__ unsigned short xs_l[16*392];
  __shared__ float lg[8*256];
  int tid = threadIdx.x;
  int t = a.t;
  if (t >= 0){
    for (int f = tid; f < 16*384; f += 256){
      int m = f/384, k = f - m*384;
      float v = 0.f;
      if (m < 8) v = (k < 256) ? a.context[m*256+k] : a.hn[m*HH + (k-256)];
      xs_l[m*392 + k] = f2bf(v);
    }
    __syncthreads();
    int wid = tid >> 6, lane = tid & 63;
    int quad = lane >> 4, col = lane & 15;
    const unsigned short* ap = xs_l + col*392 + quad*8;
    const bfrag* bp = (const bfrag*)a.WlB + ((size_t)(blockIdx.x*16 + wid*4)*12)*64 + lane;
    cfrag acc[4];
    #pragma unroll
    for (int ntl=0;ntl<4;ntl++){ acc[ntl].x=0.f; acc[ntl].y=0.f; acc[ntl].z=0.f; acc[ntl].w=0.f; }
    #pragma unroll
    for (int ks=0; ks<12; ks++){
      bfrag af = *((const bfrag*)(ap + ks*32));
      #pragma unroll
      for (int ntl=0; ntl<4; ntl++){
        bfrag bf = bp[(ntl*12 + ks)*64];
        acc[ntl] = __builtin_amdgcn_mfma_f32_16x16x32_bf16(af, bf, acc[ntl], 0,0,0);
      }
    }
    #pragma unroll
    for (int ntl=0; ntl<4; ntl++){
      int ncol = (wid*4+ntl)*16 + col;
      int v = blockIdx.x*256 + ncol;
      float bias = (v < VV) ? a.bl[v] : 0.f;
      #pragma unroll
      for (int r=0;r<4;r++){
        int m = quad*4 + r;
        if (m < 8) lg[m*256 + ncol] = (v < VV) ? (acc[ntl][r]+bias) : -1e30f;
      }
    }
    __syncthreads();
    int b = tid >> 5, i = tid & 31;
    float mx = -1e30f;
    for (int n=i; n<256; n+=32) mx = fmaxf(mx, lg[b*256+n]);
    #pragma unroll
    for (int off=16;off>=1;off>>=1) mx = fmaxf(mx, __shfl_xor(mx, off, 64));
    float sm = 0.f;
    for (int n=i; n<256; n+=32) sm += fexp(lg[b*256+n]-mx);
    #pragma unroll
    for (int off=16;off>=1;off>>=1) sm += __shfl_xor(sm, off, 64);
    if (i==0){ a.pm[blockIdx.x*BB+b] = mx; a.ps[blockIdx.x*BB+b] = sm; }
    if (tid < 8){
      int tp = a.summary[tid*T1 + t+1];
      int rel = tp - blockIdx.x*256;
      if (rel >= 0 && rel < 256) a.tgt[tid] = lg[tid*256 + rel];
    }
  }
  if (t+1 < TT && blockIdx.x < 128){
    int l8 = tid & 7;
    int e = blockIdx.x*32 + (tid>>3);
    int b = e >> 9, j = e & 511;
    int tok = a.summary[b*T1 + (t+1)];
    const float* xr = a.wv + (size_t)tok*DD;
    const float* wr = a.Wdih + (size_t)j*DD;
    float acc = 0.f;
    #pragma unroll
    for (int i2=0;i2<32;i2++){ int k = l8 + 8*i2; acc += xr[k]*wr[k]; }
    const float* hr = a.h + b*HH;
    const float* wh = a.Wdhh + (size_t)j*HH;
    #pragma unroll
    for (int i2=0;i2<16;i2++){ int k = l8 + 8*i2; acc += hr[k]*wh[k]; }
    acc += __shfl_xor(acc, 4, 64);
    acc += __shfl_xor(acc, 2, 64);
    acc += __shfl_xor(acc, 1, 64);
    if (l8==0) a.gates[b*G4 + j] = acc + a.bdih[j] + a.bdhh[j];
  }
}

// ---------------- fallback stepC (fp32, direct Wl) ----------------
struct CFArgs {
  const int* summary; const float* wv; const float* Wdih; const float* Wdhh;
  const float* bdih; const float* bdhh; const float* h; const float* hn;
  const float* context; const float* Wl; const float* bl;
  float* gates; float* pm; float* ps; float* tgt; int t;
};

__global__ void __launch_bounds__(256) k_stepC_fb(CFArgs a){
  __shared__ float xs_l[BB*384];
  __shared__ float red_l[64];
  int tid = threadIdx.x;
  int t = a.t;
  if (t >= 0){
    for (int f = tid; f < BB*384; f += 256){
      int b = f/384, k = f - b*384;
      xs_l[f] = (k < 256) ? a.context[b*256+k] : a.hn[b*HH + (k-256)];
    }
    __syncthreads();
    int v = blockIdx.x*196 + tid;
    float acc[BB];
    bool act = (tid < 196) && (v < VV);
    if (act){
      #pragma unroll
      for (int b=0;b<BB;b++) acc[b] = a.bl[v];
      const float* wr = a.Wl + (size_t)v*384;
      for (int k=0;k<384;k++){
        float w = wr[k];
        #pragma unroll
        for (int b=0;b<BB;b++) acc[b] += w*xs_l[b*384+k];
      }
      #pragma unroll
      for (int b=0;b<BB;b++) if (v == a.summary[b*T1 + t+1]) a.tgt[b] = acc[b];
    } else {
      #pragma unroll
      for (int b=0;b<BB;b++) acc[b] = -1e30f;
    }
    int wid = tid >> 6, lane = tid & 63;
    float mb[BB];
    #pragma unroll
    for (int b=0;b<BB;b++){
      float m = acc[b];
      #pragma unroll
      for (int off=32;off>=1;off>>=1) m = fmaxf(m, __shfl_xor(m, off, 64));
      if (lane==0) red_l[b*4+wid] = m;
    }
    __syncthreads();
    #pragma unroll
    for (int b=0;b<BB;b++)
      mb[b] = fmaxf(fmaxf(red_l[b*4],red_l[b*4+1]),fmaxf(red_l[b*4+2],red_l[b*4+3]));
    __syncthreads();
    #pragma unroll
    for (int b=0;b<BB;b++){
      float e = act ? fexp(acc[b]-mb[b]) : 0.f;
      #pragma unroll
      for (int off=32;off>=1;off>>=1) e += __shfl_xor(e, off, 64);
      if (lane==0) red_l[b*4+wid] = e;
    }
    __syncthreads();
    if (tid < BB){
      int b = tid;
      a.pm[blockIdx.x*BB + b] = mb[b];
      a.ps[blockIdx.x*BB + b] = red_l[b*4]+red_l[b*4+1]+red_l[b*4+2]+red_l[b*4+3];
    }
  }
  if (t+1 < TT){
    int e_sub = tid >> 4, l16 = tid & 15;
    int e = blockIdx.x*16 + e_sub;
    int b = e >> 9, j = e & 511;
    int tok = a.summary[b*T1 + (t+1)];
    const float* xr = a.wv + (size_t)tok*DD;
    const float* wr = a.Wdih + (size_t)j*DD;
    float acc = 0.f;
    #pragma unroll
    for (int i=0;i<16;i++){ int k = l16 + 16*i; acc += xr[k]*wr[k]; }
    const float* hr = a.h + b*HH;
    const float* wh = a.Wdhh + (size_t)j*HH;
    #pragma unroll
    for (int i=0;i<8;i++){ int k = l16 + 16*i; acc += hr[k]*wh[k]; }
    #pragma unroll
    for (int off=8; off>=1; off>>=1) acc += __shfl_xor(acc, off, 64);
    if (l16==0) a.gates[b*G4 + j] = acc + a.bdih[j] + a.bdhh[j];
  }
}

// ---------------- stepAB: cell + attention (blocks 0-7) + combine (block 8) --
struct ABArgs {
  const int* tlen; const int* slen; const float* gates;
  float* h; float* c; float* hn;
  const float* W1hT; const float* b1; const float* W2; const float* W1c;
  const float* TS1T; const unsigned short* ts_bf;
  float* cov; float* context; float* covloss;
  const float* pm; const float* ps; const float* tgt; float* loss;
  int t; int nblk;
};

__global__ void __launch_bounds__(512) k_stepAB(ABArgs a){
  __shared__ float uh_l[128];
  __shared__ float wc_l[128];
  __shared__ float w2_l[128];
  __shared__ float hnl[128];
  __shared__ float attn_l[512];
  __shared__ float wred[8];
  __shared__ float pc_l[512];
  __shared__ float cred[8];
  int tid = threadIdx.x;
  int t = a.t;
  if (blockIdx.x == 8){
    if (t > 0)
      dec_combine(t-1, a.nblk, a.pm, a.ps, a.tgt, a.covloss + ((t-1)&1)*BB,
                  a.slen, a.loss, cred);
    return;
  }
  int b = blockIdx.x;
  bool val = a.slen[b] > t+1;
  if (tid < 128){
    int j = tid;
    float gi = a.gates[b*G4 + j];
    float gf = a.gates[b*G4 + 128 + j];
    float gg = a.gates[b*G4 + 256 + j];
    float go = a.gates[b*G4 + 384 + j];
    float ii = sigf(gi), ff = sigf(gf), g2 = tanh_(gg), oo = sigf(go);
    float cn = ff*a.c[b*HH+j] + ii*g2;
    float hv = oo*tanh_(cn);
    hnl[j] = hv;
    a.hn[b*HH+j] = hv;
    if (val){ a.h[b*HH+j] = hv; a.c[b*HH+j] = cn; }
    wc_l[j] = a.W1c[j];
    w2_l[j] = a.W2[j];
  }
  __syncthreads();
  if (tid < 128){
    float acc = a.b1[tid];
    for (int j=0;j<128;j++) acc += hnl[j]*a.W1hT[j*128 + tid];
    uh_l[tid] = acc;
  }
  __syncthreads();
  int s = tid;
  float cv = a.cov[b*SS + s];
  float sc = 0.f;
  const float* tsp = a.TS1T + (size_t)b*128*SS + s;
  for (int k=0;k<128;k++){
    float p = tsp[(size_t)k*SS] + uh_l[k] + cv*wc_l[k];
    sc += tanh_(p)*w2_l[k];
  }
  float m = sc;
  #pragma unroll
  for (int off=32;off>=1;off>>=1) m = fmaxf(m, __shfl_xor(m, off, 64));
  int wid = tid>>6;
  if ((tid&63)==0) wred[wid] = m;
  __syncthreads();
  m = wred[0];
  #pragma unroll
  for (int wq=1;wq<8;wq++) m = fmaxf(m, wred[wq]);
  float e = fexp(sc - m);
  float ssum = e;
  #pragma unroll
  for (int off=32;off>=1;off>>=1) ssum += __shfl_xor(ssum, off, 64);
  __syncthreads();
  if ((tid&63)==0) wred[wid] = ssum;
  __syncthreads();
  ssum = 0.f;
  #pragma unroll
  for (int wq=0;wq<8;wq++) ssum += wred[wq];
  float rl = rcpf_(ssum);
  float at = e*rl;
  attn_l[s] = at;
  float cl = fminf(cv, at);
  #pragma unroll
  for (int off=32;off>=1;off>>=1) cl += __shfl_xor(cl, off, 64);
  __syncthreads();
  if ((tid&63)==0) wred[wid] = cl;
  __syncthreads();
  if (tid==0){
    float cs=0.f;
    #pragma unroll
    for (int wq=0;wq<8;wq++) cs += wred[wq];
    a.covloss[(t&1)*BB + b] = cs;
  }
  if (val) a.cov[b*SS+s] = cv + at;
  int d = tid & 255, half = tid >> 8;
  int len = a.tlen[b];
  int s0 = half*256, s1 = min(len, s0+256);
  float accd = 0.f;
  const unsigned short* tb = a.ts_bf + (size_t)b*SS*256 + d;
  for (int sp=s0; sp<s1; sp++) accd += attn_l[sp]*bf2f(tb[(size_t)sp*256]);
  pc_l[tid] = accd;
  __syncthreads();
  if (tid < 256) a.context[b*256+tid] = pc_l[tid] + pc_l[256+tid];
}

__global__ void k_fin(const float* pm, const float* ps, const float* tgt,
                      const float* covloss, const int* slen, float* loss,
                      float* out, int nblk){
  __shared__ float cred[8];
  dec_combine(TT-1, nblk, pm, ps, tgt, covloss + ((TT-1)&1)*BB, slen, loss, cred);
  if (threadIdx.x==0) out[0] = loss[0] * (1.0f/TT);
}

// ---------------- host ----------------
extern "C" void kernel_launch(void* const* d_in, const int* in_sizes, int n_in,
                              void* d_out, int out_size, void* d_ws, size_t ws_size,
                              hipStream_t stream){
  const int* text      = (const int*)d_in[0];
  const int* tlen      = (const int*)d_in[1];
  const int* summary   = (const int*)d_in[2];
  const int* slen      = (const int*)d_in[3];
  const float* wv      = (const float*)d_in[4];
  const float* Wih_f   = (const float*)d_in[5];
  const float* Whh_f   = (const float*)d_in[6];
  const float* bih_f   = (const float*)d_in[7];
  const float* bhh_f   = (const float*)d_in[8];
  const float* Wih_b   = (const float*)d_in[9];
  const float* Whh_b   = (const float*)d_in[10];
  const float* bih_b   = (const float*)d_in[11];
  const float* bhh_b   = (const float*)d_in[12];
  const float* Wdih    = (const float*)d_in[13];
  const float* Wdhh    = (const float*)d_in[14];
  const float* bdih    = (const float*)d_in[15];
  const float* bdhh    = (const float*)d_in[16];
  const float* W1      = (const float*)d_in[17];
  const float* b1      = (const float*)d_in[18];
  const float* W2      = (const float*)d_in[19];
  const float* Wl      = (const float*)d_in[21];
  const float* bl      = (const float*)d_in[22];

  char* ws = (char*)d_ws;
  size_t off = 0;
  auto alloc = [&](size_t n)->void*{
    off = (off + 255) & ~(size_t)255;
    void* p = ws + off; off += n; return p;
  };

  // persistent region
  float* WihT_f  = (float*)alloc((size_t)256*512*4);
  float* WihT_b  = (float*)alloc((size_t)256*512*4);
  unsigned* W2T_f= (unsigned*)alloc((size_t)64*512*4);
  unsigned* W2T_b= (unsigned*)alloc((size_t)64*512*4);
  float* W1hT    = (float*)alloc((size_t)128*128*4);
  float* W1aT    = (float*)alloc((size_t)256*128*4);
  float* W1c     = (float*)alloc((size_t)128*4);
  int*   ridx    = (int*)  alloc((size_t)BB*SS*4);
  float* out_f   = (float*)alloc((size_t)BB*SS*HH*4);
  float* out_r   = (float*)alloc((size_t)BB*SS*HH*4);
  unsigned short* ts_bf = (unsigned short*)alloc((size_t)BB*SS*256*2);
  float* TS1T    = (float*)alloc((size_t)BB*128*SS*4);
  float* h0      = (float*)alloc(BB*HH*4);
  float* c0      = (float*)alloc(BB*HH*4);
  float* h       = (float*)alloc(BB*HH*4);
  float* c       = (float*)alloc(BB*HH*4);
  float* hn      = (float*)alloc(BB*HH*4);
  float* cov     = (float*)alloc((size_t)BB*SS*4);
  float* gates   = (float*)alloc((size_t)BB*G4*4);
  float* context = (float*)alloc((size_t)BB*256*4);
  float* covloss = (float*)alloc(2*BB*4);
  float* tgt     = (float*)alloc(BB*4);
  float* pm      = (float*)alloc((size_t)256*BB*4);
  float* ps      = (float*)alloc((size_t)256*BB*4);
  float* loss    = (float*)alloc(4);

  // transient region: emb/Xf/Xb (encoder phase) overlaid with WlB (decoder)
  off = (off + 255) & ~(size_t)255;
  size_t trans0 = off;
  float* emb = (float*)alloc((size_t)BB*SS*DD*4);
  float* Xf  = (float*)alloc(((size_t)BB*SS*G4 + G4)*4);
  float* Xb  = (float*)alloc(((size_t)BB*SS*G4 + G4)*4);
  size_t enc_end = off;

  size_t wlB_bytes = (size_t)NTILES*12*64*16;
  short* WlB = (short*)(ws + trans0);
  int useWl = (trans0 + wlB_bytes <= ws_size && enc_end <= ws_size) ? 1 : 0;

  k_prep_small<<<1473,256,0,stream>>>(Wih_f,Wih_b,Whh_f,Whh_b,W1,W2,
                                      WihT_f,WihT_b,W2T_f,W2T_b,W1hT,W1aT,W1c);
  k_embed<<<BB*SS,64,0,stream>>>(text, tlen, wv, emb, ridx);
  k_xgemm<<<512,256,0,stream>>>(emb, ridx, WihT_f, bih_f, bhh_f, Xf, 0);
  k_xgemm<<<512,256,0,stream>>>(emb, ridx, WihT_b, bih_b, bhh_b, Xb, 1);
  k_encoder<<<dim3(8,2),512,0,stream>>>(Xf,Xb,W2T_f,W2T_b,tlen,out_f,out_r,h0,c0);
  k_post<<<dim3(8,16),256,0,stream>>>(out_f,out_r,ridx,W1aT,ts_bf,TS1T);
  if (useWl) k_prep_wlB<<<9408,256,0,stream>>>(Wl, (uint4*)WlB);
  k_init<<<8,256,0,stream>>>(h0,c0,h,c,cov,loss);

  int nblk = useWl ? CBLK : 256;

  C2Args ca;
  ca.summary=summary; ca.wv=wv; ca.Wdih=Wdih; ca.Wdhh=Wdhh; ca.bdih=bdih; ca.bdhh=bdhh;
  ca.h=h; ca.hn=hn; ca.context=context; ca.WlB=WlB; ca.bl=bl;
  ca.gates=gates; ca.pm=pm; ca.ps=ps; ca.tgt=tgt; ca.t=-1;

  CFArgs cf;
  cf.summary=summary; cf.wv=wv; cf.Wdih=Wdih; cf.Wdhh=Wdhh; cf.bdih=bdih; cf.bdhh=bdhh;
  cf.h=h; cf.hn=hn; cf.context=context; cf.Wl=Wl; cf.bl=bl;
  cf.gates=gates; cf.pm=pm; cf.ps=ps; cf.tgt=tgt; cf.t=-1;

  if (useWl) k_stepC<<<CBLK,256,0,stream>>>(ca);
  else       k_stepC_fb<<<256,256,0,stream>>>(cf);

  for (int t=0;t<TT;t++){
    ABArgs aa;
    aa.tlen=tlen; aa.slen=slen; aa.gates=gates; aa.h=h; aa.c=c; aa.hn=hn;
    aa.W1hT=W1hT; aa.b1=b1; aa.W2=W2; aa.W1c=W1c; aa.TS1T=TS1T; aa.ts_bf=ts_bf;
    aa.cov=cov; aa.context=context; aa.covloss=covloss;
    aa.pm=pm; aa.ps=ps; aa.tgt=tgt; aa.loss=loss; aa.t=t; aa.nblk=nblk;
    k_stepAB<<<9,512,0,stream>>>(aa);
    if (useWl){ ca.t = t; k_stepC<<<CBLK,256,0,stream>>>(ca); }
    else      { cf.t = t; k_stepC_fb<<<256,256,0,stream>>>(cf); }
  }
  k_fin<<<1,256,0,stream>>>(pm, ps, tgt, covloss, slen, loss, (float*)d_out, nblk);
}

// Round 3
// 9923.151 us; speedup vs baseline: 1.0181x; 1.0181x over previous
//
#include <hip/hip_runtime.h>
#include <hip/hip_bf16.h>

#define VV 50000
#define DD 256
#define HH 128
#define G4 512
#define BB 8
#define SS 512
#define TT 100
#define T1 101
#define GAMMA 1.0f
#define LOG2E 1.44269504f
#define CGRID 784            // vocab blocks: 784*64 = 50176 >= 50000
#define NTILES 3136          // 784*4 wave-tiles of 16

__device__ inline float rcpf_(float x){
#if __has_builtin(__builtin_amdgcn_rcpf)
  return __builtin_amdgcn_rcpf(x);
#else
  return 1.0f/x;
#endif
}
__device__ inline float exp2f_(float x){
#if __has_builtin(__builtin_amdgcn_exp2f)
  return __builtin_amdgcn_exp2f(x);
#else
  return exp2f(x);
#endif
}
__device__ inline float log2f_(float x){
#if __has_builtin(__builtin_amdgcn_logf)
  return __builtin_amdgcn_logf(x);
#else
  return log2f(x);
#endif
}
__device__ inline float fexp(float x){ return exp2f_(x*LOG2E); }
__device__ inline float sigf(float x){ return rcpf_(1.f + fexp(-x)); }
__device__ inline float tanh_(float x){
  x = fminf(12.f, fmaxf(-12.f, x));
  float e = fexp(2.f*x);
  return (e-1.f)*rcpf_(e+1.f);
}
__device__ inline unsigned short f2bf(float x){
  unsigned u = __float_as_uint(x);
  return (unsigned short)((u + 0x7fffu + ((u>>16)&1u)) >> 16);
}
__device__ inline unsigned pack2(float a, float b){ return (unsigned)f2bf(a) | ((unsigned)f2bf(b)<<16); }
__device__ inline float bf2f(unsigned short s){ return __uint_as_float(((unsigned)s)<<16); }
// round-half-up bf16 pack of two floats into one dword (3 VALU)
__device__ inline unsigned pack2rq(float a, float b){
#if __has_builtin(__builtin_amdgcn_perm)
  unsigned ua = __float_as_uint(a) + 0x8000u;
  unsigned ub = __float_as_uint(b) + 0x8000u;
  return __builtin_amdgcn_perm(ub, ua, 0x07060302u);
#else
  return pack2(a, b);
#endif
}

typedef __attribute__((ext_vector_type(2))) _Float16 h2v;
typedef __attribute__((ext_vector_type(8))) short bfrag;
typedef __attribute__((ext_vector_type(4))) float cfrag;

__device__ inline unsigned packh2(float a, float b){
  unsigned short ha = __builtin_bit_cast(unsigned short, (_Float16)a);
  unsigned short hb = __builtin_bit_cast(unsigned short, (_Float16)b);
  return (unsigned)ha | ((unsigned)hb<<16);
}
__device__ inline float fdot2_(unsigned a, unsigned b, float c){
#if __has_builtin(__builtin_amdgcn_fdot2)
  return __builtin_amdgcn_fdot2(__builtin_bit_cast(h2v, a), __builtin_bit_cast(h2v, b), c, false);
#else
  h2v av = __builtin_bit_cast(h2v, a), bv = __builtin_bit_cast(h2v, b);
  return c + (float)av.x*(float)bv.x + (float)av.y*(float)bv.y;
#endif
}

// ---------------- prep: small weight transposes/packs ----------------
__global__ void __launch_bounds__(256) k_prep_small(
    const float* Wih_f, const float* Wih_b, const float* Whh_f, const float* Whh_b,
    const float* W1,
    float* WihT_f, float* WihT_b, unsigned* W2T_f, unsigned* W2T_b,
    float* W1hT, float* W1aT, float* W1c){
  int i = blockIdx.x*256 + threadIdx.x;
  if (i < 131072){ int k = i>>9, j = i&511; WihT_f[i] = Wih_f[j*DD + k]; return; }
  i -= 131072;
  if (i < 131072){ int k = i>>9, j = i&511; WihT_b[i] = Wih_b[j*DD + k]; return; }
  i -= 131072;
  if (i < 32768){ int k2 = i>>9, j = i&511;
    W2T_f[i] = packh2(Whh_f[j*HH + 2*k2], Whh_f[j*HH + 2*k2+1]); return; }
  i -= 32768;
  if (i < 32768){ int k2 = i>>9, j = i&511;
    W2T_b[i] = packh2(Whh_b[j*HH + 2*k2], Whh_b[j*HH + 2*k2+1]); return; }
  i -= 32768;
  if (i < 16384){ int j = i>>7, k = i&127; W1hT[i] = W1[k*385 + 256 + j]; return; }
  i -= 16384;
  if (i < 32768){ int d = i>>7, k = i&127; W1aT[i] = W1[k*385 + d]; return; }
  i -= 32768;
  if (i < 128){ W1c[i] = W1[i*385 + 384]; return; }
}

// ---------------- prep: Wl -> bf16 MFMA B-fragment layout ----------------
// element f = (ntile*12 + ks)*64 + lane ; n = ntile*16 + (lane&15) ;
// k = ks*32 + (lane>>4)*8 + j
__global__ void __launch_bounds__(256) k_prep_wlB(const float* Wl, uint4* WlB){
  int f = blockIdx.x*256 + threadIdx.x;
  int lane = f & 63;
  int g = f >> 6;
  int ks = g % 12;
  int ntile = g / 12;
  int n = ntile*16 + (lane & 15);
  int k = ks*32 + (lane >> 4)*8;
  uint4 o = make_uint4(0,0,0,0);
  if (n < VV){
    const float* p = Wl + (size_t)n*384 + k;
    float4 w0 = ((const float4*)p)[0];
    float4 w1 = ((const float4*)p)[1];
    o.x = pack2(w0.x, w0.y); o.y = pack2(w0.z, w0.w);
    o.z = pack2(w1.x, w1.y); o.w = pack2(w1.z, w1.w);
  }
  WlB[f] = o;
}

// ---------------- embedding gather + ridx ----------------
__global__ void k_embed(const int* text, const int* tlen, const float* wv,
                        float* emb, int* ridx){
  int blk = blockIdx.x;            // b*512+s
  int b = blk>>9, s = blk&511;
  int tok = text[blk];
  const float4* src = (const float4*)(wv + (size_t)tok*DD);
  float4* dst = (float4*)(emb + (size_t)blk*DD);
  dst[threadIdx.x] = src[threadIdx.x];
  if (threadIdx.x==0){ int len = tlen[b]; ridx[blk] = (s < len) ? (len-1-s) : s; }
}

// ---------------- X = emb @ Wih^T + bih + bhh ----------------
__global__ void __launch_bounds__(256) k_xgemm(const float* emb, const int* ridx,
    const float* WihT, const float* bi, const float* bh, float* X, int rev){
  __shared__ float e_l[8][256];
  int tid = threadIdx.x;
  int g0 = blockIdx.x*8;
  int b = g0>>9;
  for (int r=0;r<8;r++){
    int s = (g0+r)&511;
    int src = rev ? ridx[b*SS + s] : s;
    e_l[r][tid] = emb[((size_t)(b*SS+src))*DD + tid];
  }
  __syncthreads();
  int j0 = tid, j1 = tid+256;
  float acc0[8], acc1[8];
  #pragma unroll
  for (int r=0;r<8;r++){ acc0[r]=0.f; acc1[r]=0.f; }
  for (int k=0;k<256;k++){
    float w0 = WihT[k*G4 + j0];
    float w1 = WihT[k*G4 + j1];
    #pragma unroll
    for (int r=0;r<8;r++){ float e = e_l[r][k]; acc0[r] += e*w0; acc1[r] += e*w1; }
  }
  float bb0 = bi[j0]+bh[j0], bb1 = bi[j1]+bh[j1];
  for (int r=0;r<8;r++){
    X[((size_t)(g0+r))*G4 + j0] = acc0[r] + bb0;
    X[((size_t)(g0+r))*G4 + j1] = acc1[r] + bb1;
  }
}

// ---------------- encoder: register-resident Whh (f16 pairs) ----------------
__global__ void __launch_bounds__(512) k_encoder(const float* Xf, const float* Xb,
    const unsigned* W2Tf, const unsigned* W2Tb, const int* tlen,
    float* out_f, float* out_r, float* h0, float* c0){
  __shared__ float g_l[512];
  __shared__ __align__(16) unsigned h2_l[64];   // 128 f16 of h
  int tid = threadIdx.x;
  int b = blockIdx.x, dir = blockIdx.y;
  const float* X = dir ? Xb : Xf;
  const unsigned* WT = dir ? W2Tb : W2Tf;
  float* out = dir ? out_r : out_f;
  unsigned w[64];
  #pragma unroll
  for (int k2=0;k2<64;k2++) w[k2] = WT[k2*G4 + tid];
  if (tid < 64) h2_l[tid] = 0u;
  float creg = 0.f;
  int len = tlen[b];
  float xx = X[(size_t)(b*SS)*G4 + tid];
  __syncthreads();
  for (int t=0;t<len;t++){
    float a0 = xx, a1 = 0.f, a2 = 0.f, a3 = 0.f;     // 4 dep chains
    const uint4* h4 = (const uint4*)h2_l;
    #pragma unroll
    for (int q=0;q<16;q++){
      uint4 hv = h4[q];
      a0 = fdot2_(w[4*q+0], hv.x, a0);
      a1 = fdot2_(w[4*q+1], hv.y, a1);
      a2 = fdot2_(w[4*q+2], hv.z, a2);
      a3 = fdot2_(w[4*q+3], hv.w, a3);
    }
    xx = X[(size_t)(b*SS+t+1)*G4 + tid];   // prefetch (buffer padded by G4)
    g_l[tid] = (a0+a1)+(a2+a3);
    __syncthreads();
    if (tid < 128){
      float ii = sigf(g_l[tid]);
      float ff = sigf(g_l[128+tid]);
      float gg = tanh_(g_l[256+tid]);
      float oo = sigf(g_l[384+tid]);
      creg = ff*creg + ii*gg;
      float hn = oo*tanh_(creg);
      out[((size_t)(b*SS+t))*HH + tid] = hn;
      ((_Float16*)h2_l)[tid] = (_Float16)hn;
      if (dir==0 && t==len-1){ h0[b*HH+tid]=hn; c0[b*HH+tid]=creg; }
    }
    __syncthreads();
  }
  for (int f = tid; f < (SS-len)*HH; f += 512){
    int s = len + (f>>7), j = f&127;
    out[((size_t)(b*SS+s))*HH + j] = 0.f;
  }
}

// ---------------- post-encoder: ts_bf16 + TS1T ----------------
__global__ void __launch_bounds__(256) k_post(const float* out_f, const float* out_r,
    const int* ridx, const float* W1aT, unsigned short* ts_bf, float* TS1T){
  __shared__ float ts_l[32*256];
  int tid = threadIdx.x;
  int b = blockIdx.x, chunk = blockIdx.y;
  int s0 = chunk*32;
  for (int it=0; it<32; ++it){
    int s = s0 + it;
    int d = tid;
    float v;
    if (d < 128) v = out_f[((size_t)(b*SS+s))*HH + d];
    else        v = out_r[((size_t)(b*SS + ridx[b*SS+s]))*HH + (d-128)];
    ts_l[it*256 + d] = v;
    ts_bf[((size_t)(b*SS+s))*256 + d] = f2bf(v);
  }
  __syncthreads();
  int k = tid & 127, half = tid >> 7;
  float acc[16];
  #pragma unroll
  for (int i=0;i<16;i++) acc[i]=0.f;
  for (int d=0;d<256;d++){
    float w = W1aT[d*128 + k];
    #pragma unroll
    for (int i=0;i<16;i++) acc[i] += ts_l[(half*16+i)*256 + d]*w;
  }
  for (int i=0;i<16;i++){
    int s = s0 + half*16 + i;
    TS1T[((size_t)(b*128+k))*SS + s] = acc[i];
  }
}

// ---------------- decoder state init ----------------
__global__ void k_init(const float* h0, const float* c0, float* h, float* c,
                       float* cov, float* loss){
  int b = blockIdx.x, tid = threadIdx.x;
  if (tid<128){ h[b*HH+tid]=h0[b*HH+tid]; c[b*HH+tid]=c0[b*HH+tid]; }
  cov[b*SS + tid] = 0.f; cov[b*SS + 256 + tid] = 0.f;
  if (b==0 && tid==0) loss[0]=0.f;
}

// ---------------- combine: LSE + loss accumulate ----------------
__device__ void dec_combine(int tc, const float* pm, const float* ps,
                            const float* tgt, const float* covloss,
                            const int* slen, float* loss, float* red){
  int tid = threadIdx.x;
  if (tid < 256){
    int b = tid >> 5, i = tid & 31;
    float m = -1e30f;
    for (int jb=i; jb<CGRID; jb+=32) m = fmaxf(m, pm[jb*BB + b]);
    #pragma unroll
    for (int off=16;off>=1;off>>=1) m = fmaxf(m, __shfl_xor(m, off, 64));
    float s = 0.f;
    for (int jb=i; jb<CGRID; jb+=32) s += ps[jb*BB + b]*fexp(pm[jb*BB+b]-m);
    #pragma unroll
    for (int off=16;off>=1;off>>=1) s += __shfl_xor(s, off, 64);
    if (i==0){
      float lse = m + log2f_(s)*0.6931472f;
      bool val = slen[b] > tc+1;
      red[b] = val ? (lse - tgt[b] + GAMMA*covloss[b]) : 0.f;
    }
  }
  __syncthreads();
  if (tid==0){
    float sum=0.f;
    #pragma unroll
    for (int b2=0;b2<BB;b2++) sum += red[b2];
    loss[0] += sum;
  }
}

// ---------------- stepC common pieces ----------------
struct CArgs {
  const int* summary; const float* wv; const float* Wdih; const float* Wdhh;
  const float* bdih; const float* bdhh; const float* h; const float* hn;
  const float* context; const short* WlB; const float* Wl; const float* bl;
  float* gates; float* pm; float* ps; float* tgt; int t;
};

__device__ inline void stepc_stage(const CArgs& a, unsigned short* xs_l){
  int tid = threadIdx.x;
  for (int f = tid; f < 16*384; f += 256){
    int m = f/384, k = f - m*384;
    float v = 0.f;
    if (m < 8) v = (k < 256) ? a.context[m*256+k] : a.hn[m*HH + (k-256)];
    xs_l[m*392 + k] = f2bf(v);
  }
}

__device__ inline void stepc_epilogue(const CArgs& a, float* lg, const cfrag& acc,
                                      int quad, int col, int wid){
  int tid = threadIdx.x;
  int n = blockIdx.x*64 + wid*16 + col;
  float bias = (n < VV) ? a.bl[n] : 0.f;
  #pragma unroll
  for (int r=0;r<4;r++){
    int m = quad*4 + r;
    if (m < 8) lg[m*64 + wid*16 + col] = (n < VV) ? (acc[r]+bias) : -1e30f;
  }
  __syncthreads();
  int b = tid >> 5, i = tid & 31;
  float v0 = lg[b*64+i], v1 = lg[b*64+32+i];
  float mx = fmaxf(v0, v1);
  #pragma unroll
  for (int off=16;off>=1;off>>=1) mx = fmaxf(mx, __shfl_xor(mx, off, 64));
  float sm = fexp(v0-mx) + fexp(v1-mx);
  #pragma unroll
  for (int off=16;off>=1;off>>=1) sm += __shfl_xor(sm, off, 64);
  if (i==0){ a.pm[blockIdx.x*BB+b] = mx; a.ps[blockIdx.x*BB+b] = sm; }
  if (tid < 8){
    int tp = a.summary[tid*T1 + a.t+1];
    int rel = tp - blockIdx.x*64;
    if (rel >= 0 && rel < 64) a.tgt[tid] = lg[tid*64 + rel];
  }
}

__device__ inline void stepc_gates(const CArgs& a){
  int tid = threadIdx.x;
  int t = a.t;
  if (t+1 < TT && blockIdx.x < 128){
    int l8 = tid & 7;
    int e = blockIdx.x*32 + (tid>>3);
    int b = e >> 9, j = e & 511;
    int tok = a.summary[b*T1 + (t+1)];
    const float* xr = a.wv + (size_t)tok*DD;
    const float* wr = a.Wdih + (size_t)j*DD;
    float acc = 0.f;
    #pragma unroll
    for (int i2=0;i2<32;i2++){ int k = l8 + 8*i2; acc += xr[k]*wr[k]; }
    const float* hr = a.h + b*HH;
    const float* wh = a.Wdhh + (size_t)j*HH;
    #pragma unroll
    for (int i2=0;i2<16;i2++){ int k = l8 + 8*i2; acc += hr[k]*wh[k]; }
    acc += __shfl_xor(acc, 4, 64);
    acc += __shfl_xor(acc, 2, 64);
    acc += __shfl_xor(acc, 1, 64);
    if (l8==0) a.gates[b*G4 + j] = acc + a.bdih[j] + a.bdhh[j];
  }
}

// ---------------- stepC: prepacked bf16 B-fragments ----------------
__global__ void __launch_bounds__(256) k_stepC(CArgs a){
  __shared__ unsigned short xs_l[16*392];
  __shared__ float lg[8*64];
  int tid = threadIdx.x;
  if (a.t >= 0){
    stepc_stage(a, xs_l);
    __syncthreads();
    int wid = tid >> 6, lane = tid & 63;
    int quad = lane >> 4, col = lane & 15;
    int vt = blockIdx.x*4 + wid;
    const unsigned short* ap = xs_l + col*392 + quad*8;
    const bfrag* bp = (const bfrag*)a.WlB + (size_t)vt*768 + lane;
    cfrag acc; acc.x=0.f; acc.y=0.f; acc.z=0.f; acc.w=0.f;
    #pragma unroll
    for (int ks=0; ks<12; ks++){
      bfrag af = *((const bfrag*)(ap + ks*32));
      bfrag bf = bp[ks*64];
      acc = __builtin_amdgcn_mfma_f32_16x16x32_bf16(af, bf, acc, 0,0,0);
    }
    stepc_epilogue(a, lg, acc, quad, col, wid);
  }
  stepc_gates(a);
}

// ---------------- stepC: direct fp32 Wl, on-the-fly bf16 ----------------
__global__ void __launch_bounds__(256) k_stepC_dir(CArgs a){
  __shared__ unsigned short xs_l[16*392];
  __shared__ float lg[8*64];
  int tid = threadIdx.x;
  if (a.t >= 0){
    stepc_stage(a, xs_l);
    __syncthreads();
    int wid = tid >> 6, lane = tid & 63;
    int quad = lane >> 4, col = lane & 15;
    int vt = blockIdx.x*4 + wid;
    int n = vt*16 + col;
    int nc = (n < VV) ? n : (VV-1);
    const unsigned short* ap = xs_l + col*392 + quad*8;
    const float* wr = a.Wl + (size_t)nc*384 + quad*8;
    cfrag acc; acc.x=0.f; acc.y=0.f; acc.z=0.f; acc.w=0.f;
    #pragma unroll
    for (int ks=0; ks<12; ks++){
      float4 w0 = *((const float4*)(wr + ks*32));
      float4 w1 = *((const float4*)(wr + ks*32 + 4));
      uint4 ub = make_uint4(pack2rq(w0.x,w0.y), pack2rq(w0.z,w0.w),
                            pack2rq(w1.x,w1.y), pack2rq(w1.z,w1.w));
      bfrag bf = __builtin_bit_cast(bfrag, ub);
      bfrag af = *((const bfrag*)(ap + ks*32));
      acc = __builtin_amdgcn_mfma_f32_16x16x32_bf16(af, bf, acc, 0,0,0);
    }
    stepc_epilogue(a, lg, acc, quad, col, wid);
  }
  stepc_gates(a);
}

// ---------------- stepAB: cell + attention (blocks 0-7) + combine (block 8) --
struct ABArgs {
  const int* tlen; const int* slen; const float* gates;
  float* h; float* c; float* hn;
  const float* W1hT; const float* b1; const float* W2; const float* W1c;
  const float* TS1T; const unsigned short* ts_bf;
  float* cov; float* context; float* covloss;
  const float* pm; const float* ps; const float* tgt; float* loss;
  int t;
};

__global__ void __launch_bounds__(512) k_stepAB(ABArgs a){
  __shared__ float uh_l[128];
  __shared__ float wc_l[128];
  __shared__ float w2_l[128];
  __shared__ float hnl[128];
  __shared__ float attn_l[512];
  __shared__ float wred[8];
  __shared__ float pc_l[512];
  __shared__ float cred[8];
  int tid = threadIdx.x;
  int t = a.t;
  if (blockIdx.x == 8){
    if (t > 0)
      dec_combine(t-1, a.pm, a.ps, a.tgt, a.covloss + ((t-1)&1)*BB,
                  a.slen, a.loss, cred);
    return;
  }
  int b = blockIdx.x;
  bool val = a.slen[b] > t+1;
  if (tid < 128){
    int j = tid;
    float gi = a.gates[b*G4 + j];
    float gf = a.gates[b*G4 + 128 + j];
    float gg = a.gates[b*G4 + 256 + j];
    float go = a.gates[b*G4 + 384 + j];
    float ii = sigf(gi), ff = sigf(gf), g2 = tanh_(gg), oo = sigf(go);
    float cn = ff*a.c[b*HH+j] + ii*g2;
    float hv = oo*tanh_(cn);
    hnl[j] = hv;
    a.hn[b*HH+j] = hv;
    if (val){ a.h[b*HH+j] = hv; a.c[b*HH+j] = cn; }
    wc_l[j] = a.W1c[j];
    w2_l[j] = a.W2[j];
  }
  __syncthreads();
  if (tid < 128){
    float acc = a.b1[tid];
    for (int j=0;j<128;j++) acc += hnl[j]*a.W1hT[j*128 + tid];
    uh_l[tid] = acc;
  }
  __syncthreads();
  int s = tid;
  float cv = a.cov[b*SS + s];
  float sc = 0.f;
  const float* tsp = a.TS1T + (size_t)b*128*SS + s;
  for (int k=0;k<128;k++){
    float p = tsp[(size_t)k*SS] + uh_l[k] + cv*wc_l[k];
    sc += tanh_(p)*w2_l[k];
  }
  float m = sc;
  #pragma unroll
  for (int off=32;off>=1;off>>=1) m = fmaxf(m, __shfl_xor(m, off, 64));
  int wid = tid>>6;
  if ((tid&63)==0) wred[wid] = m;
  __syncthreads();
  m = wred[0];
  #pragma unroll
  for (int wq=1;wq<8;wq++) m = fmaxf(m, wred[wq]);
  float e = fexp(sc - m);
  float ssum = e;
  #pragma unroll
  for (int off=32;off>=1;off>>=1) ssum += __shfl_xor(ssum, off, 64);
  __syncthreads();
  if ((tid&63)==0) wred[wid] = ssum;
  __syncthreads();
  ssum = 0.f;
  #pragma unroll
  for (int wq=0;wq<8;wq++) ssum += wred[wq];
  float rl = rcpf_(ssum);
  float at = e*rl;
  attn_l[s] = at;
  float cl = fminf(cv, at);
  #pragma unroll
  for (int off=32;off>=1;off>>=1) cl += __shfl_xor(cl, off, 64);
  __syncthreads();
  if ((tid&63)==0) wred[wid] = cl;
  __syncthreads();
  if (tid==0){
    float cs=0.f;
    #pragma unroll
    for (int wq=0;wq<8;wq++) cs += wred[wq];
    a.covloss[(t&1)*BB + b] = cs;
  }
  if (val) a.cov[b*SS+s] = cv + at;
  int d = tid & 255, half = tid >> 8;
  int len = a.tlen[b];
  int s0 = half*256, s1 = min(len, s0+256);
  float accd = 0.f;
  const unsigned short* tb = a.ts_bf + (size_t)b*SS*256 + d;
  for (int sp=s0; sp<s1; sp++) accd += attn_l[sp]*bf2f(tb[(size_t)sp*256]);
  pc_l[tid] = accd;
  __syncthreads();
  if (tid < 256) a.context[b*256+tid] = pc_l[tid] + pc_l[256+tid];
}

__global__ void k_fin(const float* pm, const float* ps, const float* tgt,
                      const float* covloss, const int* slen, float* loss,
                      float* out){
  __shared__ float cred[8];
  dec_combine(TT-1, pm, ps, tgt, covloss + ((TT-1)&1)*BB, slen, loss, cred);
  if (threadIdx.x==0) out[0] = loss[0] * (1.0f/TT);
}

// ---------------- host ----------------
extern "C" void kernel_launch(void* const* d_in, const int* in_sizes, int n_in,
                              void* d_out, int out_size, void* d_ws, size_t ws_size,
                              hipStream_t stream){
  const int* text      = (const int*)d_in[0];
  const int* tlen      = (const int*)d_in[1];
  const int* summary   = (const int*)d_in[2];
  const int* slen      = (const int*)d_in[3];
  const float* wv      = (const float*)d_in[4];
  const float* Wih_f   = (const float*)d_in[5];
  const float* Whh_f   = (const float*)d_in[6];
  const float* bih_f   = (const float*)d_in[7];
  const float* bhh_f   = (const float*)d_in[8];
  const float* Wih_b   = (const float*)d_in[9];
  const float* Whh_b   = (const float*)d_in[10];
  const float* bih_b   = (const float*)d_in[11];
  const float* bhh_b   = (const float*)d_in[12];
  const float* Wdih    = (const float*)d_in[13];
  const float* Wdhh    = (const float*)d_in[14];
  const float* bdih    = (const float*)d_in[15];
  const float* bdhh    = (const float*)d_in[16];
  const float* W1      = (const float*)d_in[17];
  const float* b1      = (const float*)d_in[18];
  const float* W2      = (const float*)d_in[19];
  const float* Wl      = (const float*)d_in[21];
  const float* bl      = (const float*)d_in[22];

  char* ws = (char*)d_ws;
  size_t off = 0;
  auto alloc = [&](size_t n)->void*{
    off = (off + 255) & ~(size_t)255;
    void* p = ws + off; off += n; return p;
  };

  // ---- decode-persistent region (small; ~10.4 MB) ----
  float* W1hT    = (float*)alloc((size_t)128*128*4);
  float* W1c     = (float*)alloc((size_t)128*4);
  unsigned short* ts_bf = (unsigned short*)alloc((size_t)BB*SS*256*2);
  float* TS1T    = (float*)alloc((size_t)BB*128*SS*4);
  float* h0      = (float*)alloc(BB*HH*4);
  float* c0      = (float*)alloc(BB*HH*4);
  float* h       = (float*)alloc(BB*HH*4);
  float* c       = (float*)alloc(BB*HH*4);
  float* hn      = (float*)alloc(BB*HH*4);
  float* cov     = (float*)alloc((size_t)BB*SS*4);
  float* gates   = (float*)alloc((size_t)BB*G4*4);
  float* context = (float*)alloc((size_t)BB*256*4);
  float* covloss = (float*)alloc(2*BB*4);
  float* tgt     = (float*)alloc(BB*4);
  float* pm      = (float*)alloc((size_t)CGRID*BB*4);
  float* ps      = (float*)alloc((size_t)CGRID*BB*4);
  float* loss    = (float*)alloc(4);

  // ---- encoder-transient region (overlaid by WlB during decode) ----
  off = (off + 255) & ~(size_t)255;
  size_t trans0 = off;
  float* emb     = (float*)alloc((size_t)BB*SS*DD*4);
  float* Xf      = (float*)alloc(((size_t)BB*SS*G4 + G4)*4);
  float* Xb      = (float*)alloc(((size_t)BB*SS*G4 + G4)*4);
  float* WihT_f  = (float*)alloc((size_t)256*512*4);
  float* WihT_b  = (float*)alloc((size_t)256*512*4);
  unsigned* W2T_f= (unsigned*)alloc((size_t)64*512*4);
  unsigned* W2T_b= (unsigned*)alloc((size_t)64*512*4);
  float* out_f   = (float*)alloc((size_t)BB*SS*HH*4);
  float* out_r   = (float*)alloc((size_t)BB*SS*HH*4);
  float* W1aT    = (float*)alloc((size_t)256*128*4);
  int*   ridx    = (int*)  alloc((size_t)BB*SS*4);

  size_t wlB_bytes = (size_t)NTILES*12*64*16;   // 38.5 MB
  short* WlB = (short*)(ws + trans0);
  int useWl = (trans0 + wlB_bytes <= ws_size) ? 1 : 0;

  k_prep_small<<<1473,256,0,stream>>>(Wih_f,Wih_b,Whh_f,Whh_b,W1,
                                      WihT_f,WihT_b,W2T_f,W2T_b,W1hT,W1aT,W1c);
  k_embed<<<BB*SS,64,0,stream>>>(text, tlen, wv, emb, ridx);
  k_xgemm<<<512,256,0,stream>>>(emb, ridx, WihT_f, bih_f, bhh_f, Xf, 0);
  k_xgemm<<<512,256,0,stream>>>(emb, ridx, WihT_b, bih_b, bhh_b, Xb, 1);
  k_encoder<<<dim3(8,2),512,0,stream>>>(Xf,Xb,W2T_f,W2T_b,tlen,out_f,out_r,h0,c0);
  k_post<<<dim3(8,16),256,0,stream>>>(out_f,out_r,ridx,W1aT,ts_bf,TS1T);
  if (useWl) k_prep_wlB<<<9408,256,0,stream>>>(Wl, (uint4*)WlB);  // transients dead now
  k_init<<<8,256,0,stream>>>(h0,c0,h,c,cov,loss);

  CArgs ca;
  ca.summary=summary; ca.wv=wv; ca.Wdih=Wdih; ca.Wdhh=Wdhh; ca.bdih=bdih; ca.bdhh=bdhh;
  ca.h=h; ca.hn=hn; ca.context=context; ca.WlB=WlB; ca.Wl=Wl; ca.bl=bl;
  ca.gates=gates; ca.pm=pm; ca.ps=ps; ca.tgt=tgt; ca.t=-1;

  if (useWl) k_stepC<<<CGRID,256,0,stream>>>(ca);
  else       k_stepC_dir<<<CGRID,256,0,stream>>>(ca);

  for (int t=0;t<TT;t++){
    ABArgs aa;
    aa.tlen=tlen; aa.slen=slen; aa.gates=gates; aa.h=h; aa.c=c; aa.hn=hn;
    aa.W1hT=W1hT; aa.b1=b1; aa.W2=W2; aa.W1c=W1c; aa.TS1T=TS1T; aa.ts_bf=ts_bf;
    aa.cov=cov; aa.context=context; aa.covloss=covloss;
    aa.pm=pm; aa.ps=ps; aa.tgt=tgt; aa.loss=loss; aa.t=t;
    k_stepAB<<<9,512,0,stream>>>(aa);
    ca.t = t;
    if (useWl) k_stepC<<<CGRID,256,0,stream>>>(ca);
    else       k_stepC_dir<<<CGRID,256,0,stream>>>(ca);
  }
  k_fin<<<1,256,0,stream>>>(pm, ps, tgt, covloss, slen, loss, (float*)d_out);
}

// Round 4
// 8460.863 us; speedup vs baseline: 1.1941x; 1.1728x over previous
//
#include <hip/hip_runtime.h>
#include <hip/hip_bf16.h>

#define VV 50000
#define DD 256
#define HH 128
#define G4 512
#define BB 8
#define SS 512
#define TT 100
#define T1 101
#define GAMMA 1.0f
#define LOG2E 1.44269504f
#define CGB 224              // Cgemm blocks
#define TPB 14               // vocab 16-tiles per Cgemm block (224*14*16 = 50176)
#define NTILES (CGB*TPB)
#define NBLK (9+CGB)         // 0-7 AB, 8 combine, 9..232 Cgemm

__device__ inline float rcpf_(float x){
#if __has_builtin(__builtin_amdgcn_rcpf)
  return __builtin_amdgcn_rcpf(x);
#else
  return 1.0f/x;
#endif
}
__device__ inline float exp2f_(float x){
#if __has_builtin(__builtin_amdgcn_exp2f)
  return __builtin_amdgcn_exp2f(x);
#else
  return exp2f(x);
#endif
}
__device__ inline float log2f_(float x){
#if __has_builtin(__builtin_amdgcn_logf)
  return __builtin_amdgcn_logf(x);
#else
  return log2f(x);
#endif
}
__device__ inline float fexp(float x){ return exp2f_(x*LOG2E); }
__device__ inline float sigf(float x){ return rcpf_(1.f + fexp(-x)); }
__device__ inline float tanh_(float x){
  x = fminf(12.f, fmaxf(-12.f, x));
  float e = fexp(2.f*x);
  return (e-1.f)*rcpf_(e+1.f);
}
__device__ inline unsigned short f2bf(float x){
  unsigned u = __float_as_uint(x);
  return (unsigned short)((u + 0x7fffu + ((u>>16)&1u)) >> 16);
}
__device__ inline unsigned pack2(float a, float b){ return (unsigned)f2bf(a) | ((unsigned)f2bf(b)<<16); }
__device__ inline float bf2f(unsigned short s){ return __uint_as_float(((unsigned)s)<<16); }
__device__ inline unsigned pack2rq(float a, float b){
#if __has_builtin(__builtin_amdgcn_perm)
  unsigned ua = __float_as_uint(a) + 0x8000u;
  unsigned ub = __float_as_uint(b) + 0x8000u;
  return __builtin_amdgcn_perm(ub, ua, 0x07060302u);
#else
  return pack2(a, b);
#endif
}

typedef __attribute__((ext_vector_type(2))) _Float16 h2v;
typedef __attribute__((ext_vector_type(8))) short bfrag;
typedef __attribute__((ext_vector_type(4))) float cfrag;

__device__ inline unsigned packh2(float a, float b){
  unsigned short ha = __builtin_bit_cast(unsigned short, (_Float16)a);
  unsigned short hb = __builtin_bit_cast(unsigned short, (_Float16)b);
  return (unsigned)ha | ((unsigned)hb<<16);
}
__device__ inline float fdot2_(unsigned a, unsigned b, float c){
#if __has_builtin(__builtin_amdgcn_fdot2)
  return __builtin_amdgcn_fdot2(__builtin_bit_cast(h2v, a), __builtin_bit_cast(h2v, b), c, false);
#else
  h2v av = __builtin_bit_cast(h2v, a), bv = __builtin_bit_cast(h2v, b);
  return c + (float)av.x*(float)bv.x + (float)av.y*(float)bv.y;
#endif
}

// ---------------- device-scope grid barrier (sense-reversal) ----------------
__device__ inline void gbar(unsigned* bar){
  __syncthreads();
  if (threadIdx.x == 0){
    __threadfence();
    unsigned gen = __hip_atomic_load(bar+1, __ATOMIC_RELAXED, __HIP_MEMORY_SCOPE_AGENT);
    unsigned old = __hip_atomic_fetch_add(bar, 1u, __ATOMIC_ACQ_REL, __HIP_MEMORY_SCOPE_AGENT);
    if (old == (unsigned)(NBLK-1)){
      __hip_atomic_store(bar, 0u, __ATOMIC_RELAXED, __HIP_MEMORY_SCOPE_AGENT);
      __hip_atomic_fetch_add(bar+1, 1u, __ATOMIC_RELEASE, __HIP_MEMORY_SCOPE_AGENT);
    } else {
      while (__hip_atomic_load(bar+1, __ATOMIC_RELAXED, __HIP_MEMORY_SCOPE_AGENT) == gen)
        __builtin_amdgcn_s_sleep(8);
    }
    __threadfence();
  }
  __syncthreads();
}

// ---------------- prep: small weight transposes/packs ----------------
__global__ void __launch_bounds__(256) k_prep_small(
    const float* Wih_f, const float* Wih_b, const float* Whh_f, const float* Whh_b,
    const float* W1, const float* Wdih, const float* Wdhh,
    float* WihT_f, float* WihT_b, unsigned* W2T_f, unsigned* W2T_b,
    float* W1hT, float* W1aT, float* W1c, unsigned* Wd2){
  int i = blockIdx.x*256 + threadIdx.x;
  if (i < 131072){ int k = i>>9, j = i&511; WihT_f[i] = Wih_f[j*DD + k]; return; }
  i -= 131072;
  if (i < 131072){ int k = i>>9, j = i&511; WihT_b[i] = Wih_b[j*DD + k]; return; }
  i -= 131072;
  if (i < 32768){ int k2 = i>>9, j = i&511;
    W2T_f[i] = packh2(Whh_f[j*HH + 2*k2], Whh_f[j*HH + 2*k2+1]); return; }
  i -= 32768;
  if (i < 32768){ int k2 = i>>9, j = i&511;
    W2T_b[i] = packh2(Whh_b[j*HH + 2*k2], Whh_b[j*HH + 2*k2+1]); return; }
  i -= 32768;
  if (i < 16384){ int j = i>>7, k = i&127; W1hT[i] = W1[k*385 + 256 + j]; return; }
  i -= 16384;
  if (i < 32768){ int d = i>>7, k = i&127; W1aT[i] = W1[k*385 + d]; return; }
  i -= 32768;
  if (i < 128){ W1c[i] = W1[i*385 + 384]; return; }
  i -= 128;
  if (i < 98304){
    int j = i/192, k2 = i - j*192;
    unsigned v;
    if (k2 < 128) v = packh2(Wdih[j*DD + 2*k2], Wdih[j*DD + 2*k2+1]);
    else { int q = k2-128; v = packh2(Wdhh[j*HH + 2*q], Wdhh[j*HH + 2*q+1]); }
    Wd2[i] = v;
  }
}

// ---------------- prep: Wl -> bf16 MFMA B-fragment layout ----------------
__global__ void __launch_bounds__(256) k_prep_wlB(const float* Wl, uint4* WlB){
  int f = blockIdx.x*256 + threadIdx.x;
  int lane = f & 63;
  int g = f >> 6;
  int ks = g % 12;
  int ntile = g / 12;
  int n = ntile*16 + (lane & 15);
  int k = ks*32 + (lane >> 4)*8;
  uint4 o = make_uint4(0,0,0,0);
  if (n < VV){
    const float* p = Wl + (size_t)n*384 + k;
    float4 w0 = ((const float4*)p)[0];
    float4 w1 = ((const float4*)p)[1];
    o.x = pack2(w0.x, w0.y); o.y = pack2(w0.z, w0.w);
    o.z = pack2(w1.x, w1.y); o.w = pack2(w1.z, w1.w);
  }
  WlB[f] = o;
}

// ---------------- embedding gather + ridx ----------------
__global__ void k_embed(const int* text, const int* tlen, const float* wv,
                        float* emb, int* ridx){
  int blk = blockIdx.x;
  int b = blk>>9, s = blk&511;
  int tok = text[blk];
  const float4* src = (const float4*)(wv + (size_t)tok*DD);
  float4* dst = (float4*)(emb + (size_t)blk*DD);
  dst[threadIdx.x] = src[threadIdx.x];
  if (threadIdx.x==0){ int len = tlen[b]; ridx[blk] = (s < len) ? (len-1-s) : s; }
}

// ---------------- X = emb @ Wih^T + bih + bhh ----------------
__global__ void __launch_bounds__(256) k_xgemm(const float* emb, const int* ridx,
    const float* WihT, const float* bi, const float* bh, float* X, int rev){
  __shared__ float e_l[8][256];
  int tid = threadIdx.x;
  int g0 = blockIdx.x*8;
  int b = g0>>9;
  for (int r=0;r<8;r++){
    int s = (g0+r)&511;
    int src = rev ? ridx[b*SS + s] : s;
    e_l[r][tid] = emb[((size_t)(b*SS+src))*DD + tid];
  }
  __syncthreads();
  int j0 = tid, j1 = tid+256;
  float acc0[8], acc1[8];
  #pragma unroll
  for (int r=0;r<8;r++){ acc0[r]=0.f; acc1[r]=0.f; }
  for (int k=0;k<256;k++){
    float w0 = WihT[k*G4 + j0];
    float w1 = WihT[k*G4 + j1];
    #pragma unroll
    for (int r=0;r<8;r++){ float e = e_l[r][k]; acc0[r] += e*w0; acc1[r] += e*w1; }
  }
  float bb0 = bi[j0]+bh[j0], bb1 = bi[j1]+bh[j1];
  for (int r=0;r<8;r++){
    X[((size_t)(g0+r))*G4 + j0] = acc0[r] + bb0;
    X[((size_t)(g0+r))*G4 + j1] = acc1[r] + bb1;
  }
}

// ---------------- encoder: register-resident Whh, X preload x8 ----------------
__global__ void __launch_bounds__(512) k_encoder(const float* Xf, const float* Xb,
    const unsigned* W2Tf, const unsigned* W2Tb, const int* tlen,
    float* out_f, float* out_r, float* h0, float* c0){
  __shared__ float g_l[512];
  __shared__ __align__(16) unsigned h2_l[64];
  int tid = threadIdx.x;
  int b = blockIdx.x, dir = blockIdx.y;
  const float* X = dir ? Xb : Xf;
  const unsigned* WT = dir ? W2Tb : W2Tf;
  float* out = dir ? out_r : out_f;
  unsigned w[64];
  #pragma unroll
  for (int k2=0;k2<64;k2++) w[k2] = WT[k2*G4 + tid];
  if (tid < 64) h2_l[tid] = 0u;
  float creg = 0.f;
  int len = tlen[b];
  __syncthreads();
  for (int t0=0;t0<len;t0+=8){
    float x8[8];
    #pragma unroll
    for (int i=0;i<8;i++) x8[i] = X[(size_t)(b*SS+t0+i)*G4 + tid];
    #pragma unroll 1
    for (int i=0;i<8;i++){
      int t = t0+i;
      if (t >= len) break;
      float a0 = x8[i], a1 = 0.f, a2 = 0.f, a3 = 0.f;
      const uint4* h4 = (const uint4*)h2_l;
      #pragma unroll
      for (int q=0;q<16;q++){
        uint4 hv = h4[q];
        a0 = fdot2_(w[4*q+0], hv.x, a0);
        a1 = fdot2_(w[4*q+1], hv.y, a1);
        a2 = fdot2_(w[4*q+2], hv.z, a2);
        a3 = fdot2_(w[4*q+3], hv.w, a3);
      }
      g_l[tid] = (a0+a1)+(a2+a3);
      __syncthreads();
      if (tid < 128){
        float ii = sigf(g_l[tid]);
        float ff = sigf(g_l[128+tid]);
        float gg = tanh_(g_l[256+tid]);
        float oo = sigf(g_l[384+tid]);
        creg = ff*creg + ii*gg;
        float hn = oo*tanh_(creg);
        out[((size_t)(b*SS+t))*HH + tid] = hn;
        ((_Float16*)h2_l)[tid] = (_Float16)hn;
        if (dir==0 && t==len-1){ h0[b*HH+tid]=hn; c0[b*HH+tid]=creg; }
      }
      __syncthreads();
    }
  }
  for (int f = tid; f < (SS-len)*HH; f += 512){
    int s = len + (f>>7), j = f&127;
    out[((size_t)(b*SS+s))*HH + j] = 0.f;
  }
}

// ---------------- post-encoder: ts_bf16 + TS1T ----------------
__global__ void __launch_bounds__(256) k_post(const float* out_f, const float* out_r,
    const int* ridx, const float* W1aT, unsigned short* ts_bf, float* TS1T){
  __shared__ float ts_l[32*256];
  int tid = threadIdx.x;
  int b = blockIdx.x, chunk = blockIdx.y;
  int s0 = chunk*32;
  for (int it=0; it<32; ++it){
    int s = s0 + it;
    int d = tid;
    float v;
    if (d < 128) v = out_f[((size_t)(b*SS+s))*HH + d];
    else        v = out_r[((size_t)(b*SS + ridx[b*SS+s]))*HH + (d-128)];
    ts_l[it*256 + d] = v;
    ts_bf[((size_t)(b*SS+s))*256 + d] = f2bf(v);
  }
  __syncthreads();
  int k = tid & 127, half = tid >> 7;
  float acc[16];
  #pragma unroll
  for (int i=0;i<16;i++) acc[i]=0.f;
  for (int d=0;d<256;d++){
    float w = W1aT[d*128 + k];
    #pragma unroll
    for (int i=0;i<16;i++) acc[i] += ts_l[(half*16+i)*256 + d]*w;
  }
  for (int i=0;i<16;i++){
    int s = s0 + half*16 + i;
    TS1T[((size_t)(b*128+k))*SS + s] = acc[i];
  }
}

// ---------------- init: state + gates(0) + barrier ----------------
__global__ void __launch_bounds__(256) k_init(const int* summary, const float* wv,
    const float* h0, const float* c0, const float* Wdih, const float* Wdhh,
    const float* bdih, const float* bdhh,
    float* c, float* hm, float* cov, float* gates, unsigned* bar){
  __shared__ float x_l[256];
  __shared__ float h_l[128];
  int b = blockIdx.x, tid = threadIdx.x;
  int tok = summary[b*T1];
  x_l[tid] = wv[(size_t)tok*DD + tid];
  if (tid < 128){
    float hv = h0[b*HH+tid];
    h_l[tid] = hv; hm[b*HH+tid] = hv; c[b*HH+tid] = c0[b*HH+tid];
  }
  cov[b*SS + tid] = 0.f; cov[b*SS + 256 + tid] = 0.f;
  if (b==0 && tid < 2) bar[tid] = 0u;
  __syncthreads();
  #pragma unroll
  for (int half=0; half<2; half++){
    int jj = tid + half*256;
    float acc = bdih[jj] + bdhh[jj];
    const float4* wr = (const float4*)(Wdih + (size_t)jj*DD);
    #pragma unroll 8
    for (int q=0;q<64;q++){
      float4 wv4 = wr[q];
      acc += wv4.x*x_l[4*q] + wv4.y*x_l[4*q+1] + wv4.z*x_l[4*q+2] + wv4.w*x_l[4*q+3];
    }
    const float4* wh = (const float4*)(Wdhh + (size_t)jj*HH);
    #pragma unroll 8
    for (int q=0;q<32;q++){
      float4 wv4 = wh[q];
      acc += wv4.x*h_l[4*q] + wv4.y*h_l[4*q+1] + wv4.z*h_l[4*q+2] + wv4.w*h_l[4*q+3];
    }
    gates[b*G4 + jj] = acc;
  }
}

// ---------------- persistent decoder ----------------
struct PArgs {
  const int* summary; const int* tlen; const int* slen;
  const float* wv;
  const float* TS1T; const unsigned short* ts_bf;
  const float* W1hT; const float* W1c; const float* W2; const float* b1;
  const unsigned* Wd2; const float* bdih; const float* bdhh;
  const short* WlB; const float* Wl; const float* bl;
  float* c; float* hm; float* hn; float* ctx; float* cov; float* gates;
  float* covloss; float* pm; float* ps; unsigned* bar; float* out;
};

struct LdsAB {
  float hnl[128], hml[128], uh[128], wc[128], w2[128];
  float attn[512], xl[256];
  float wredA[4], wredB[4], wredC[4];
  unsigned x2[128], hm2[64];
};
struct LdsCG { unsigned short xs[16*392]; float rm[32], rs[32]; };
struct LdsCB { float tgt[16]; float red[8]; float loss; };
union LdsU { LdsAB ab; LdsCG cg; LdsCB cb; };

template<int USEWL>
__global__ void __launch_bounds__(256,4) k_decode(PArgs a){
  __shared__ LdsU L;
  int bid = blockIdx.x, tid = threadIdx.x;
  for (int it = 0; it <= TT+1; ++it){
    if (bid < 8){
      int t = it;
      if (t < TT){
        int b = bid;
        bool valid = a.slen[b] > t+1;
        if (tid < 128){
          int j = tid;
          float gi=a.gates[b*G4+j], gf=a.gates[b*G4+128+j],
                gg=a.gates[b*G4+256+j], go=a.gates[b*G4+384+j];
          float ii=sigf(gi), ff=sigf(gf), g2=tanh_(gg), oo=sigf(go);
          float cn = ff*a.c[b*HH+j] + ii*g2;
          float hv = oo*tanh_(cn);
          L.ab.hnl[j] = hv;
          a.hn[(t&1)*BB*HH + b*HH + j] = hv;
          if (valid) a.c[b*HH+j] = cn;
          float hmv = valid ? hv : a.hm[b*HH+j];
          a.hm[b*HH+j] = hmv;
          L.ab.hml[j] = hmv;
          L.ab.wc[j] = a.W1c[j];
          L.ab.w2[j] = a.W2[j];
        }
        __syncthreads();
        if (tid < 128){
          float acc = a.b1[tid];
          const float* wp = a.W1hT + tid;
          for (int j=0;j<128;j++) acc += L.ab.hnl[j]*wp[j*128];
          L.ab.uh[tid] = acc;
        }
        __syncthreads();
        float cv0 = a.cov[b*SS+tid], cv1 = a.cov[b*SS+256+tid];
        float sc0 = 0.f, sc1 = 0.f;
        const float* tsp = a.TS1T + (size_t)b*HH*SS;
        for (int k=0;k<128;k++){
          float ub = L.ab.uh[k], wc = L.ab.wc[k], w2 = L.ab.w2[k];
          sc0 += tanh_(tsp[k*SS+tid]       + ub + cv0*wc)*w2;
          sc1 += tanh_(tsp[k*SS+256+tid]   + ub + cv1*wc)*w2;
        }
        int wid = tid>>6;
        float m = fmaxf(sc0, sc1);
        #pragma unroll
        for (int off=32;off>=1;off>>=1) m = fmaxf(m, __shfl_xor(m, off, 64));
        if ((tid&63)==0) L.ab.wredA[wid] = m;
        __syncthreads();
        m = fmaxf(fmaxf(L.ab.wredA[0],L.ab.wredA[1]),
                  fmaxf(L.ab.wredA[2],L.ab.wredA[3]));
        float e0 = fexp(sc0-m), e1 = fexp(sc1-m);
        float es = e0+e1;
        #pragma unroll
        for (int off=32;off>=1;off>>=1) es += __shfl_xor(es, off, 64);
        if ((tid&63)==0) L.ab.wredB[wid] = es;
        __syncthreads();
        float ssum = L.ab.wredB[0]+L.ab.wredB[1]+L.ab.wredB[2]+L.ab.wredB[3];
        float rl = rcpf_(ssum);
        float a0 = e0*rl, a1 = e1*rl;
        L.ab.attn[tid] = a0; L.ab.attn[256+tid] = a1;
        float cl = fminf(cv0,a0) + fminf(cv1,a1);
        #pragma unroll
        for (int off=32;off>=1;off>>=1) cl += __shfl_xor(cl, off, 64);
        if ((tid&63)==0) L.ab.wredC[wid] = cl;
        if (valid){ a.cov[b*SS+tid] = cv0+a0; a.cov[b*SS+256+tid] = cv1+a1; }
        __syncthreads();
        if (tid==0)
          a.covloss[(t&3)*BB+b] = L.ab.wredC[0]+L.ab.wredC[1]+L.ab.wredC[2]+L.ab.wredC[3];
        int len = a.tlen[b];
        float accd = 0.f;
        const unsigned short* tb = a.ts_bf + (size_t)b*SS*256 + tid;
        for (int s=0;s<len;s++) accd += L.ab.attn[s]*bf2f(tb[(size_t)s*256]);
        a.ctx[(t&1)*BB*256 + b*256 + tid] = accd;
        if (t+1 < TT){
          int tok = a.summary[b*T1 + t+1];
          L.ab.xl[tid] = a.wv[(size_t)tok*DD + tid];
          __syncthreads();
          if (tid < 128) L.ab.x2[tid] = packh2(L.ab.xl[2*tid], L.ab.xl[2*tid+1]);
          if (tid < 64)  L.ab.hm2[tid] = packh2(L.ab.hml[2*tid], L.ab.hml[2*tid+1]);
          __syncthreads();
          #pragma unroll
          for (int half=0; half<2; half++){
            int jj = tid + half*256;
            float acc  = a.bdih[jj] + a.bdhh[jj];
            float acc2 = 0.f;
            const uint2* wp = (const uint2*)(a.Wd2 + (size_t)jj*192);
            #pragma unroll 8
            for (int q=0;q<64;q++){
              uint2 w = wp[q];
              acc  = fdot2_(w.x, L.ab.x2[2*q],   acc);
              acc2 = fdot2_(w.y, L.ab.x2[2*q+1], acc2);
            }
            const uint2* wh = (const uint2*)(a.Wd2 + (size_t)jj*192 + 128);
            #pragma unroll 8
            for (int q=0;q<32;q++){
              uint2 w = wh[q];
              acc  = fdot2_(w.x, L.ab.hm2[2*q],   acc);
              acc2 = fdot2_(w.y, L.ab.hm2[2*q+1], acc2);
            }
            a.gates[b*G4 + jj] = acc + acc2;
          }
        }
      }
    } else if (bid == 8){
      if (it==0 && tid==0) L.cb.loss = 0.f;
      int ts = it-1;
      if (ts >= 0 && ts < TT){
        int b = tid>>5, l = tid&31;
        int tp = a.summary[b*T1 + ts+1];
        int par = ts&1;
        float acc = 0.f;
        for (int i=0;i<12;i++){
          int k = l + 32*i;
          float x = (k<256) ? a.ctx[par*BB*256 + b*256 + k]
                            : a.hn[par*BB*HH + b*HH + (k-256)];
          float w = a.Wl[(size_t)tp*384 + k];
          float wr = USEWL ? bf2f(f2bf(w))
                           : __uint_as_float((__float_as_uint(w)+0x8000u)&0xffff0000u);
          acc += bf2f(f2bf(x))*wr;
        }
        #pragma unroll
        for (int off=16;off>=1;off>>=1) acc += __shfl_xor(acc, off, 64);
        if (l==0) L.cb.tgt[par*BB+b] = acc + a.bl[tp];
      }
      int cs = it-2;
      if (cs >= 0 && cs < TT){
        int b = tid>>5, l = tid&31;
        int slot = cs&1;
        const float* pmp = a.pm + slot*CGB*BB;
        const float* psp = a.ps + slot*CGB*BB;
        float m = -1e30f;
        for (int jb=l; jb<CGB; jb+=32) m = fmaxf(m, pmp[jb*BB+b]);
        #pragma unroll
        for (int off=16;off>=1;off>>=1) m = fmaxf(m, __shfl_xor(m, off, 64));
        float s = 0.f;
        for (int jb=l; jb<CGB; jb+=32) s += psp[jb*BB+b]*fexp(pmp[jb*BB+b]-m);
        #pragma unroll
        for (int off=16;off>=1;off>>=1) s += __shfl_xor(s, off, 64);
        if (l==0){
          float lse = m + log2f_(s)*0.6931472f;
          bool val = a.slen[b] > cs+1;
          L.cb.red[b] = val ? (lse - L.cb.tgt[slot*BB+b] + GAMMA*a.covloss[(cs&3)*BB+b]) : 0.f;
        }
        __syncthreads();
        if (tid==0){
          float sum = 0.f;
          #pragma unroll
          for (int b2=0;b2<BB;b2++) sum += L.cb.red[b2];
          L.cb.loss += sum;
        }
      }
      if (it==TT+1 && tid==0) a.out[0] = L.cb.loss*(1.0f/TT);
    } else {
      int s = it-1;
      if (s >= 0 && s < TT){
        int cb = bid-9;
        int par = s&1;
        for (int f=tid; f<16*384; f+=256){
          int m2 = f/384, k = f - m2*384;
          float v = 0.f;
          if (m2 < 8) v = (k<256) ? a.ctx[par*BB*256 + m2*256 + k]
                                  : a.hn[par*BB*HH + m2*HH + (k-256)];
          L.cg.xs[m2*392 + k] = f2bf(v);
        }
        __syncthreads();
        int wid = tid>>6, lane = tid&63, quad = lane>>4, col = lane&15;
        const unsigned short* ap = L.cg.xs + col*392 + quad*8;
        float mr[4], sr[4];
        #pragma unroll
        for (int r=0;r<4;r++){ mr[r] = -1e30f; sr[r] = 0.f; }
        for (int lt=wid; lt<TPB; lt+=4){
          int g = cb*TPB + lt;
          int n = g*16 + col;
          cfrag acc; acc.x=0.f; acc.y=0.f; acc.z=0.f; acc.w=0.f;
          if (USEWL){
            const bfrag* bp = ((const bfrag*)a.WlB) + (size_t)g*768 + lane;
            #pragma unroll
            for (int ks=0; ks<12; ks++){
              bfrag af = *((const bfrag*)(ap + ks*32));
              bfrag bf = bp[ks*64];
              acc = __builtin_amdgcn_mfma_f32_16x16x32_bf16(af, bf, acc, 0,0,0);
            }
          } else {
            int nc = (n < VV) ? n : (VV-1);
            const float* wr = a.Wl + (size_t)nc*384 + quad*8;
            #pragma unroll
            for (int ks=0; ks<12; ks++){
              float4 w0 = *((const float4*)(wr + ks*32));
              float4 w1 = *((const float4*)(wr + ks*32 + 4));
              uint4 ub = make_uint4(pack2rq(w0.x,w0.y), pack2rq(w0.z,w0.w),
                                    pack2rq(w1.x,w1.y), pack2rq(w1.z,w1.w));
              bfrag bf = __builtin_bit_cast(bfrag, ub);
              bfrag af = *((const bfrag*)(ap + ks*32));
              acc = __builtin_amdgcn_mfma_f32_16x16x32_bf16(af, bf, acc, 0,0,0);
            }
          }
          float bias = (n < VV) ? a.bl[n] : 0.f;
          #pragma unroll
          for (int r=0;r<4;r++){
            int mrow = quad*4 + r;
            float v = (mrow < 8 && n < VV) ? (acc[r]+bias) : -1e30f;
            float nm = fmaxf(mr[r], v);
            float ev = (v <= -1e29f) ? 0.f : fexp(v-nm);
            sr[r] = sr[r]*fexp(mr[r]-nm) + ev;
            mr[r] = nm;
          }
        }
        #pragma unroll
        for (int off=1; off<16; off<<=1){
          #pragma unroll
          for (int r=0;r<4;r++){
            float m2 = __shfl_xor(mr[r], off, 64);
            float s2 = __shfl_xor(sr[r], off, 64);
            float nm = fmaxf(mr[r], m2);
            sr[r] = sr[r]*fexp(mr[r]-nm) + s2*fexp(m2-nm);
            mr[r] = nm;
          }
        }
        if (col==0 && quad<2){
          #pragma unroll
          for (int r=0;r<4;r++){
            L.cg.rm[wid*8 + quad*4 + r] = mr[r];
            L.cg.rs[wid*8 + quad*4 + r] = sr[r];
          }
        }
        __syncthreads();
        if (tid < 8){
          float M = -1e30f, S = 0.f;
          #pragma unroll
          for (int w4=0; w4<4; w4++){
            float m2 = L.cg.rm[w4*8+tid], s2 = L.cg.rs[w4*8+tid];
            float nm = fmaxf(M, m2);
            S = S*fexp(M-nm) + s2*fexp(m2-nm);
            M = nm;
          }
          a.pm[par*CGB*BB + cb*BB + tid] = M;
          a.ps[par*CGB*BB + cb*BB + tid] = S;
        }
      }
    }
    gbar(a.bar);
  }
}

// ---------------- host ----------------
extern "C" void kernel_launch(void* const* d_in, const int* in_sizes, int n_in,
                              void* d_out, int out_size, void* d_ws, size_t ws_size,
                              hipStream_t stream){
  const int* text      = (const int*)d_in[0];
  const int* tlen      = (const int*)d_in[1];
  const int* summary   = (const int*)d_in[2];
  const int* slen      = (const int*)d_in[3];
  const float* wv      = (const float*)d_in[4];
  const float* Wih_f   = (const float*)d_in[5];
  const float* Whh_f   = (const float*)d_in[6];
  const float* bih_f   = (const float*)d_in[7];
  const float* bhh_f   = (const float*)d_in[8];
  const float* Wih_b   = (const float*)d_in[9];
  const float* Whh_b   = (const float*)d_in[10];
  const float* bih_b   = (const float*)d_in[11];
  const float* bhh_b   = (const float*)d_in[12];
  const float* Wdih    = (const float*)d_in[13];
  const float* Wdhh    = (const float*)d_in[14];
  const float* bdih    = (const float*)d_in[15];
  const float* bdhh    = (const float*)d_in[16];
  const float* W1      = (const float*)d_in[17];
  const float* b1      = (const float*)d_in[18];
  const float* W2      = (const float*)d_in[19];
  const float* Wl      = (const float*)d_in[21];
  const float* bl      = (const float*)d_in[22];

  char* ws = (char*)d_ws;
  size_t off = 0;
  auto alloc = [&](size_t n)->void*{
    off = (off + 255) & ~(size_t)255;
    void* p = ws + off; off += n; return p;
  };

  // ---- decode-persistent region (~4.6 MB) ----
  float* W1hT    = (float*)alloc((size_t)128*128*4);
  float* W1c     = (float*)alloc((size_t)128*4);
  unsigned* Wd2  = (unsigned*)alloc((size_t)512*192*4);
  unsigned short* ts_bf = (unsigned short*)alloc((size_t)BB*SS*256*2);
  float* TS1T    = (float*)alloc((size_t)BB*128*SS*4);
  float* h0      = (float*)alloc(BB*HH*4);
  float* c0      = (float*)alloc(BB*HH*4);
  float* c       = (float*)alloc(BB*HH*4);
  float* hm      = (float*)alloc(BB*HH*4);
  float* hn      = (float*)alloc(2*BB*HH*4);
  float* cov     = (float*)alloc((size_t)BB*SS*4);
  float* gates   = (float*)alloc((size_t)BB*G4*4);
  float* ctx     = (float*)alloc(2*(size_t)BB*256*4);
  float* covloss = (float*)alloc(4*BB*4);
  float* pm      = (float*)alloc(2*(size_t)CGB*BB*4);
  float* ps      = (float*)alloc(2*(size_t)CGB*BB*4);
  unsigned* bar  = (unsigned*)alloc(256);

  // ---- encoder-transient region (overlaid by WlB during decode) ----
  off = (off + 255) & ~(size_t)255;
  size_t trans0 = off;
  float* emb     = (float*)alloc((size_t)BB*SS*DD*4);
  float* Xf      = (float*)alloc(((size_t)BB*SS*G4 + 8*G4)*4);
  float* Xb      = (float*)alloc(((size_t)BB*SS*G4 + 8*G4)*4);
  float* WihT_f  = (float*)alloc((size_t)256*512*4);
  float* WihT_b  = (float*)alloc((size_t)256*512*4);
  unsigned* W2T_f= (unsigned*)alloc((size_t)64*512*4);
  unsigned* W2T_b= (unsigned*)alloc((size_t)64*512*4);
  float* out_f   = (float*)alloc((size_t)BB*SS*HH*4);
  float* out_r   = (float*)alloc((size_t)BB*SS*HH*4);
  float* W1aT    = (float*)alloc((size_t)256*128*4);
  int*   ridx    = (int*)  alloc((size_t)BB*SS*4);

  size_t wlB_bytes = (size_t)NTILES*12*64*16;   // 38.5 MB
  short* WlB = (short*)(ws + trans0);
  int useWl = (trans0 + wlB_bytes <= ws_size) ? 1 : 0;

  k_prep_small<<<1857,256,0,stream>>>(Wih_f,Wih_b,Whh_f,Whh_b,W1,Wdih,Wdhh,
                                      WihT_f,WihT_b,W2T_f,W2T_b,W1hT,W1aT,W1c,Wd2);
  k_embed<<<BB*SS,64,0,stream>>>(text, tlen, wv, emb, ridx);
  k_xgemm<<<512,256,0,stream>>>(emb, ridx, WihT_f, bih_f, bhh_f, Xf, 0);
  k_xgemm<<<512,256,0,stream>>>(emb, ridx, WihT_b, bih_b, bhh_b, Xb, 1);
  k_encoder<<<dim3(8,2),512,0,stream>>>(Xf,Xb,W2T_f,W2T_b,tlen,out_f,out_r,h0,c0);
  k_post<<<dim3(8,16),256,0,stream>>>(out_f,out_r,ridx,W1aT,ts_bf,TS1T);
  if (useWl) k_prep_wlB<<<9408,256,0,stream>>>(Wl, (uint4*)WlB);
  k_init<<<8,256,0,stream>>>(summary,wv,h0,c0,Wdih,Wdhh,bdih,bdhh,c,hm,cov,gates,bar);

  PArgs a;
  a.summary=summary; a.tlen=tlen; a.slen=slen; a.wv=wv;
  a.TS1T=TS1T; a.ts_bf=ts_bf;
  a.W1hT=W1hT; a.W1c=W1c; a.W2=W2; a.b1=b1;
  a.Wd2=Wd2; a.bdih=bdih; a.bdhh=bdhh;
  a.WlB=WlB; a.Wl=Wl; a.bl=bl;
  a.c=c; a.hm=hm; a.hn=hn; a.ctx=ctx; a.cov=cov; a.gates=gates;
  a.covloss=covloss; a.pm=pm; a.ps=ps; a.bar=bar; a.out=(float*)d_out;

  if (useWl) k_decode<1><<<NBLK,256,0,stream>>>(a);
  else       k_decode<0><<<NBLK,256,0,stream>>>(a);
}

// Round 5
// 3316.290 us; speedup vs baseline: 3.0465x; 2.5513x over previous
//
#include <hip/hip_runtime.h>
#include <hip/hip_bf16.h>

#define VV 50000
#define DD 256
#define HH 128
#define G4 512
#define BB 8
#define SS 512
#define TT 100
#define T1 101
#define GAMMA 1.0f
#define LOG2E 1.44269504f
#define CGB 224              // GEMM blocks
#define TPB 14               // vocab 16-tiles per GEMM block (224*14*16 = 50176)
#define NBLK (17+CGB)        // 0-7 AB, 8-15 CTX, 16 combine, 17..240 GEMM

__device__ inline float rcpf_(float x){
#if __has_builtin(__builtin_amdgcn_rcpf)
  return __builtin_amdgcn_rcpf(x);
#else
  return 1.0f/x;
#endif
}
__device__ inline float exp2f_(float x){
#if __has_builtin(__builtin_amdgcn_exp2f)
  return __builtin_amdgcn_exp2f(x);
#else
  return exp2f(x);
#endif
}
__device__ inline float log2f_(float x){
#if __has_builtin(__builtin_amdgcn_logf)
  return __builtin_amdgcn_logf(x);
#else
  return log2f(x);
#endif
}
__device__ inline float fexp(float x){ return exp2f_(x*LOG2E); }
__device__ inline float sigf(float x){ return rcpf_(1.f + fexp(-x)); }
__device__ inline float tanh_(float x){
  x = fminf(12.f, fmaxf(-12.f, x));
  float e = fexp(2.f*x);
  return (e-1.f)*rcpf_(e+1.f);
}
__device__ inline unsigned short f2bf(float x){
  unsigned u = __float_as_uint(x);
  return (unsigned short)((u + 0x7fffu + ((u>>16)&1u)) >> 16);
}
__device__ inline float bf2f(unsigned short s){ return __uint_as_float(((unsigned)s)<<16); }
__device__ inline float bfrnd(float x){
  return __uint_as_float((__float_as_uint(x)+0x8000u)&0xffff0000u);
}
__device__ inline unsigned pack2rq(float a, float b){
#if __has_builtin(__builtin_amdgcn_perm)
  unsigned ua = __float_as_uint(a) + 0x8000u;
  unsigned ub = __float_as_uint(b) + 0x8000u;
  return __builtin_amdgcn_perm(ub, ua, 0x07060302u);
#else
  unsigned ra = (__float_as_uint(a)+0x8000u)>>16;
  unsigned rb = (__float_as_uint(b)+0x8000u)>>16;
  return ra | (rb<<16);
#endif
}

typedef __attribute__((ext_vector_type(2))) _Float16 h2v;
typedef __attribute__((ext_vector_type(8))) short bfrag;
typedef __attribute__((ext_vector_type(4))) float cfrag;

__device__ inline unsigned packh2(float a, float b){
  unsigned short ha = __builtin_bit_cast(unsigned short, (_Float16)a);
  unsigned short hb = __builtin_bit_cast(unsigned short, (_Float16)b);
  return (unsigned)ha | ((unsigned)hb<<16);
}
__device__ inline float fdot2_(unsigned a, unsigned b, float c){
#if __has_builtin(__builtin_amdgcn_fdot2)
  return __builtin_amdgcn_fdot2(__builtin_bit_cast(h2v, a), __builtin_bit_cast(h2v, b), c, false);
#else
  h2v av = __builtin_bit_cast(h2v, a), bv = __builtin_bit_cast(h2v, b);
  return c + (float)av.x*(float)bv.x + (float)av.y*(float)bv.y;
#endif
}
__device__ inline float hlo(unsigned u){ return (float)__builtin_bit_cast(h2v, u).x; }
__device__ inline float hhi(unsigned u){ return (float)__builtin_bit_cast(h2v, u).y; }

// ---------------- device-scope grid barrier (sense-reversal) ----------------
__device__ inline void gbar(unsigned* bar){
  __syncthreads();
  if (threadIdx.x == 0){
    __threadfence();
    unsigned gen = __hip_atomic_load(bar+1, __ATOMIC_RELAXED, __HIP_MEMORY_SCOPE_AGENT);
    unsigned old = __hip_atomic_fetch_add(bar, 1u, __ATOMIC_ACQ_REL, __HIP_MEMORY_SCOPE_AGENT);
    if (old == (unsigned)(NBLK-1)){
      __hip_atomic_store(bar, 0u, __ATOMIC_RELAXED, __HIP_MEMORY_SCOPE_AGENT);
      __hip_atomic_fetch_add(bar+1, 1u, __ATOMIC_RELEASE, __HIP_MEMORY_SCOPE_AGENT);
    } else {
      while (__hip_atomic_load(bar+1, __ATOMIC_RELAXED, __HIP_MEMORY_SCOPE_AGENT) == gen)
        __builtin_amdgcn_s_sleep(4);
    }
    __threadfence();
  }
  __syncthreads();
}

// ---------------- prep: small weight transposes/packs ----------------
__global__ void __launch_bounds__(256) k_prep_small(
    const float* Wih_f, const float* Wih_b, const float* Whh_f, const float* Whh_b,
    const float* W1, const float* Wdhh,
    float* WihT_f, float* WihT_b, unsigned* W2T_f, unsigned* W2T_b,
    float* W1aT, float* W1c, unsigned* W1h2, unsigned* Wdh2T){
  int i = blockIdx.x*256 + threadIdx.x;
  if (i < 131072){ int k = i>>9, j = i&511; WihT_f[i] = Wih_f[j*DD + k]; return; }
  i -= 131072;
  if (i < 131072){ int k = i>>9, j = i&511; WihT_b[i] = Wih_b[j*DD + k]; return; }
  i -= 131072;
  if (i < 32768){ int k2 = i>>9, j = i&511;
    W2T_f[i] = packh2(Whh_f[j*HH + 2*k2], Whh_f[j*HH + 2*k2+1]); return; }
  i -= 32768;
  if (i < 32768){ int k2 = i>>9, j = i&511;
    W2T_b[i] = packh2(Whh_b[j*HH + 2*k2], Whh_b[j*HH + 2*k2+1]); return; }
  i -= 32768;
  if (i < 32768){ int d = i>>7, k = i&127; W1aT[i] = W1[k*385 + d]; return; }
  i -= 32768;
  if (i < 128){ W1c[i] = W1[i*385 + 384]; return; }
  i -= 128;
  if (i < 8192){ int j2 = i>>7, col = i&127;
    W1h2[i] = packh2(W1[col*385 + 256 + 2*j2], W1[col*385 + 256 + 2*j2+1]); return; }
  i -= 8192;
  if (i < 32768){ int q = i>>9, jj = i&511;
    Wdh2T[i] = packh2(Wdhh[jj*HH + 2*q], Wdhh[jj*HH + 2*q+1]); return; }
}

// ---------------- Xd[t][b][j] = Wdih@x + bdih + bdhh ; also zero barrier -----
__global__ void __launch_bounds__(512) k_xd(const int* summary, const float* wv,
    const float* Wdih, const float* bdih, const float* bdhh,
    float* Xd, unsigned* bar){
  __shared__ float xsl[8][256];
  int t = blockIdx.x, tid = threadIdx.x;
  for (int f=tid; f<2048; f+=512){
    int b = f>>8, k = f&255;
    xsl[b][k] = wv[(size_t)summary[b*T1 + t]*DD + k];
  }
  if (blockIdx.x==0 && tid<2) bar[tid] = 0u;
  __syncthreads();
  int jj = tid;
  float base = bdih[jj] + bdhh[jj];
  const float4* wr = (const float4*)(Wdih + (size_t)jj*DD);
  float acc[8];
  #pragma unroll
  for (int b=0;b<8;b++) acc[b]=0.f;
  for (int q=0;q<64;q++){
    float4 w = wr[q];
    #pragma unroll
    for (int b=0;b<8;b++)
      acc[b] += w.x*xsl[b][4*q] + w.y*xsl[b][4*q+1] + w.z*xsl[b][4*q+2] + w.w*xsl[b][4*q+3];
  }
  #pragma unroll
  for (int b=0;b<8;b++) Xd[((size_t)t*BB + b)*G4 + jj] = base + acc[b];
}

// ---------------- embedding gather + ridx ----------------
__global__ void k_embed(const int* text, const int* tlen, const float* wv,
                        float* emb, int* ridx){
  int blk = blockIdx.x;
  int b = blk>>9, s = blk&511;
  int tok = text[blk];
  const float4* src = (const float4*)(wv + (size_t)tok*DD);
  float4* dst = (float4*)(emb + (size_t)blk*DD);
  dst[threadIdx.x] = src[threadIdx.x];
  if (threadIdx.x==0){ int len = tlen[b]; ridx[blk] = (s < len) ? (len-1-s) : s; }
}

// ---------------- X = emb @ Wih^T + bih + bhh ----------------
__global__ void __launch_bounds__(256) k_xgemm(const float* emb, const int* ridx,
    const float* WihT, const float* bi, const float* bh, float* X, int rev){
  __shared__ float e_l[8][256];
  int tid = threadIdx.x;
  int g0 = blockIdx.x*8;
  int b = g0>>9;
  for (int r=0;r<8;r++){
    int s = (g0+r)&511;
    int src = rev ? ridx[b*SS + s] : s;
    e_l[r][tid] = emb[((size_t)(b*SS+src))*DD + tid];
  }
  __syncthreads();
  int j0 = tid, j1 = tid+256;
  float acc0[8], acc1[8];
  #pragma unroll
  for (int r=0;r<8;r++){ acc0[r]=0.f; acc1[r]=0.f; }
  for (int k=0;k<256;k++){
    float w0 = WihT[k*G4 + j0];
    float w1 = WihT[k*G4 + j1];
    #pragma unroll
    for (int r=0;r<8;r++){ float e = e_l[r][k]; acc0[r] += e*w0; acc1[r] += e*w1; }
  }
  float bb0 = bi[j0]+bh[j0], bb1 = bi[j1]+bh[j1];
  for (int r=0;r<8;r++){
    X[((size_t)(g0+r))*G4 + j0] = acc0[r] + bb0;
    X[((size_t)(g0+r))*G4 + j1] = acc1[r] + bb1;
  }
}

// ---------------- encoder: register-resident Whh (f16), X preload x8 --------
__global__ void __launch_bounds__(512) k_encoder(const float* Xf, const float* Xb,
    const unsigned* W2Tf, const unsigned* W2Tb, const int* tlen,
    float* out_f, float* out_r, float* h0, float* c0){
  __shared__ float g_l[512];
  __shared__ __align__(16) unsigned h2_l[64];
  int tid = threadIdx.x;
  int b = blockIdx.x, dir = blockIdx.y;
  const float* X = dir ? Xb : Xf;
  const unsigned* WT = dir ? W2Tb : W2Tf;
  float* out = dir ? out_r : out_f;
  unsigned w[64];
  #pragma unroll
  for (int k2=0;k2<64;k2++) w[k2] = WT[k2*G4 + tid];
  if (tid < 64) h2_l[tid] = 0u;
  float creg = 0.f;
  int len = tlen[b];
  __syncthreads();
  for (int t0=0;t0<len;t0+=8){
    float x8[8];
    #pragma unroll
    for (int i=0;i<8;i++) x8[i] = X[(size_t)(b*SS+t0+i)*G4 + tid];
    #pragma unroll 1
    for (int i=0;i<8;i++){
      int t = t0+i;
      if (t >= len) break;
      float a0 = x8[i], a1 = 0.f, a2 = 0.f, a3 = 0.f;
      const uint4* h4 = (const uint4*)h2_l;
      #pragma unroll
      for (int q=0;q<16;q++){
        uint4 hv = h4[q];
        a0 = fdot2_(w[4*q+0], hv.x, a0);
        a1 = fdot2_(w[4*q+1], hv.y, a1);
        a2 = fdot2_(w[4*q+2], hv.z, a2);
        a3 = fdot2_(w[4*q+3], hv.w, a3);
      }
      g_l[tid] = (a0+a1)+(a2+a3);
      __syncthreads();
      if (tid < 128){
        float ii = sigf(g_l[tid]);
        float ff = sigf(g_l[128+tid]);
        float gg = tanh_(g_l[256+tid]);
        float oo = sigf(g_l[384+tid]);
        creg = ff*creg + ii*gg;
        float hn = oo*tanh_(creg);
        out[((size_t)(b*SS+t))*HH + tid] = hn;
        ((_Float16*)h2_l)[tid] = (_Float16)hn;
        if (dir==0 && t==len-1){ h0[b*HH+tid]=hn; c0[b*HH+tid]=creg; }
      }
      __syncthreads();
    }
  }
  for (int f = tid; f < (SS-len)*HH; f += 512){
    int s = len + (f>>7), j = f&127;
    out[((size_t)(b*SS+s))*HH + j] = 0.f;
  }
}

// ------- post-encoder: ts_h (f16 pairs over s) + TS1Th (f16 pairs over k) ----
__global__ void __launch_bounds__(256) k_post(const float* out_f, const float* out_r,
    const int* ridx, const float* W1aT, unsigned* ts_h, unsigned* TS1Th){
  __shared__ float ts_l[128*33 + 64];   // also reused as pk[k][33]
  int tid = threadIdx.x;
  int b = blockIdx.x, chunk = blockIdx.y;
  int s0 = chunk*32;
  for (int it=0; it<32; ++it){
    int s = s0 + it;
    int d = tid;
    float v;
    if (d < 128) v = out_f[((size_t)(b*SS+s))*HH + d];
    else        v = out_r[((size_t)(b*SS + ridx[b*SS+s]))*HH + (d-128)];
    ts_l[it*256 + d] = v;
  }
  __syncthreads();
  // ts_h[b][half][s2][d]
  for (int f=tid; f<16*256; f+=256){
    int it2 = f>>8, d = f&255;
    unsigned p = packh2(ts_l[(2*it2)*256 + d], ts_l[(2*it2+1)*256 + d]);
    ts_h[((((size_t)b*2 + (s0>>8))*128) + (((s0&255)>>1) + it2))*256 + d] = p;
  }
  int k = tid & 127, half = tid >> 7;
  float acc[16];
  #pragma unroll
  for (int i=0;i<16;i++) acc[i]=0.f;
  for (int d=0;d<256;d++){
    float w = W1aT[d*128 + k];
    #pragma unroll
    for (int i=0;i<16;i++) acc[i] += ts_l[(half*16+i)*256 + d]*w;
  }
  __syncthreads();
  #pragma unroll
  for (int i=0;i<16;i++) ts_l[k*33 + half*16 + i] = acc[i];
  __syncthreads();
  for (int f=tid; f<64*32; f+=256){
    int k2 = f>>5, sl = f&31;
    unsigned p = packh2(ts_l[(2*k2)*33 + sl], ts_l[(2*k2+1)*33 + sl]);
    TS1Th[((size_t)b*64 + k2)*512 + (s0 + sl)] = p;
  }
}

// ---------------- persistent decoder ----------------
struct PArgs {
  const int* summary; const int* slen;
  const float* Xd; const unsigned* TS1Th; const unsigned* ts_h;
  const unsigned* W1h2g; const float* W1c; const float* W2; const float* b1;
  const unsigned* Wdh2T; const float* Wl; const float* bl;
  const float* h0; const float* c0;
  float* hn; float* ctx; float* attn; float* covloss;
  float* pm; float* ps; unsigned* bar; float* out;
};

struct LdsAB {
  unsigned W1h2[8192];
  float gates[512];
  float hnl[128], hml[128], uh[128];
  unsigned hn2[64], hm2[64];
  float wc[128], w2l[128], b1l[128];
  float wredA[8], wredB[8], wredC[8];
};
struct LdsCG { unsigned short xs[16*392]; float rm[64], rs[64]; };
struct LdsCTX { float at[512]; float part[512]; };
struct LdsCB { float tgt[16]; float red[8]; float loss; };
union LdsU { LdsAB ab; LdsCG cg; LdsCTX cx; LdsCB cb; };

__global__ void __launch_bounds__(512,2) k_decode(PArgs a){
  __shared__ LdsU L;
  int bid = blockIdx.x, tid = threadIdx.x;

  if (bid < 8){
    // ================= AB: cell + attention + gates =================
    int b = bid;
    int slenb = a.slen[b];
    // one-time setup
    if (tid < 128){
      L.ab.wc[tid]  = a.W1c[tid];
      L.ab.w2l[tid] = a.W2[tid];
      L.ab.b1l[tid] = a.b1[tid];
    }
    for (int f=tid; f<8192; f+=512) L.ab.W1h2[f] = a.W1h2g[f];
    unsigned ts2[64];
    #pragma unroll
    for (int k2=0;k2<64;k2++) ts2[k2] = a.TS1Th[((size_t)b*64 + k2)*512 + tid];
    unsigned wdh[64];
    #pragma unroll
    for (int q=0;q<64;q++) wdh[q] = a.Wdh2T[q*512 + tid];
    float creg = 0.f, hmreg = 0.f;
    if (tid < 128){
      creg  = a.c0[b*HH+tid];
      hmreg = a.h0[b*HH+tid];
      L.ab.hml[tid] = hmreg;
    }
    float cv = 0.f;
    __syncthreads();
    if (tid < 64) L.ab.hm2[tid] = packh2(L.ab.hml[2*tid], L.ab.hml[2*tid+1]);
    __syncthreads();
    {
      float g = a.Xd[(size_t)0*BB*G4 + b*G4 + tid];
      #pragma unroll
      for (int q=0;q<64;q++) g = fdot2_(wdh[q], L.ab.hm2[q], g);
      L.ab.gates[tid] = g;
    }
    __syncthreads();

    for (int it=0; it<=TT+2; ++it){
      int t = it;
      if (t < TT){
        int tn = (t+1 < TT) ? t+1 : 0;
        float xdn = a.Xd[(size_t)tn*BB*G4 + b*G4 + tid];   // prefetch
        bool valid = (slenb > t+1);
        if (tid < 128){
          float gi = L.ab.gates[tid];
          float gf = L.ab.gates[128+tid];
          float gg = L.ab.gates[256+tid];
          float go = L.ab.gates[384+tid];
          float ii = sigf(gi), ff = sigf(gf), g2 = tanh_(gg), oo = sigf(go);
          float cn = ff*creg + ii*g2;
          float hv = oo*tanh_(cn);
          if (valid) creg = cn;
          hmreg = valid ? hv : hmreg;
          L.ab.hnl[tid] = hv;
          L.ab.hml[tid] = hmreg;
          a.hn[((size_t)(t&3)*BB + b)*HH + tid] = hv;
        }
        __syncthreads();
        if (tid < 64){
          L.ab.hn2[tid] = packh2(L.ab.hnl[2*tid], L.ab.hnl[2*tid+1]);
          L.ab.hm2[tid] = packh2(L.ab.hml[2*tid], L.ab.hml[2*tid+1]);
        }
        __syncthreads();
        if (tid < 128){
          float acc = L.ab.b1l[tid];
          #pragma unroll
          for (int j2=0;j2<64;j2++) acc = fdot2_(L.ab.W1h2[j2*128+tid], L.ab.hn2[j2], acc);
          L.ab.uh[tid] = acc;
        }
        __syncthreads();
        float sc = 0.f;
        #pragma unroll
        for (int k2=0;k2<64;k2++){
          unsigned tp = ts2[k2];
          float p0 = hlo(tp) + L.ab.uh[2*k2]   + cv*L.ab.wc[2*k2];
          float p1 = hhi(tp) + L.ab.uh[2*k2+1] + cv*L.ab.wc[2*k2+1];
          sc += tanh_(p0)*L.ab.w2l[2*k2];
          sc += tanh_(p1)*L.ab.w2l[2*k2+1];
        }
        int wid = tid>>6;
        float m = sc;
        #pragma unroll
        for (int off=32;off>=1;off>>=1) m = fmaxf(m, __shfl_xor(m, off, 64));
        if ((tid&63)==0) L.ab.wredA[wid] = m;
        __syncthreads();
        m = L.ab.wredA[0];
        #pragma unroll
        for (int w8=1;w8<8;w8++) m = fmaxf(m, L.ab.wredA[w8]);
        float e = fexp(sc - m);
        float es = e;
        #pragma unroll
        for (int off=32;off>=1;off>>=1) es += __shfl_xor(es, off, 64);
        if ((tid&63)==0) L.ab.wredB[wid] = es;
        __syncthreads();
        float ssum = 0.f;
        #pragma unroll
        for (int w8=0;w8<8;w8++) ssum += L.ab.wredB[w8];
        float at = e * rcpf_(ssum);
        a.attn[((size_t)(t&1)*BB + b)*SS + tid] = at;
        float cl = fminf(cv, at);
        #pragma unroll
        for (int off=32;off>=1;off>>=1) cl += __shfl_xor(cl, off, 64);
        if ((tid&63)==0) L.ab.wredC[wid] = cl;
        __syncthreads();
        if (tid==0){
          float cs = 0.f;
          #pragma unroll
          for (int w8=0;w8<8;w8++) cs += L.ab.wredC[w8];
          a.covloss[(t&3)*BB + b] = cs;
        }
        if (valid) cv += at;
        if (t+1 < TT){
          float g = xdn;
          #pragma unroll
          for (int q=0;q<64;q++) g = fdot2_(wdh[q], L.ab.hm2[q], g);
          __syncthreads();
          L.ab.gates[tid] = g;
        }
      }
      gbar(a.bar);
    }
  } else if (bid < 16){
    // ================= CTX: context = attn @ ts (lag 1) =================
    int b = bid-8;
    int d = tid & 255, half = tid >> 8;
    unsigned tsr[128];
    #pragma unroll
    for (int s2=0;s2<128;s2++)
      tsr[s2] = a.ts_h[((((size_t)b*2 + half)*128) + s2)*256 + d];
    for (int it=0; it<=TT+2; ++it){
      int s = it-1;
      if (s >= 0 && s < TT){
        L.cx.at[tid] = a.attn[((size_t)(s&1)*BB + b)*SS + tid];
        __syncthreads();
        float acc = 0.f;
        const float* ap = L.cx.at + half*256;
        #pragma unroll
        for (int s2=0;s2<128;s2++){
          unsigned tp = tsr[s2];
          acc += hlo(tp)*ap[2*s2] + hhi(tp)*ap[2*s2+1];
        }
        L.cx.part[tid] = acc;
        __syncthreads();
        if (tid < 256)
          a.ctx[((size_t)(s&1)*BB + b)*256 + tid] = L.cx.part[tid] + L.cx.part[256+tid];
      }
      gbar(a.bar);
    }
  } else if (bid == 16){
    // ================= CB: target logit (lag 2) + LSE/loss (lag 3) =========
    int b = tid >> 6, l = tid & 63;
    int slenb = a.slen[b];
    if (tid == 0) L.cb.loss = 0.f;
    __syncthreads();
    for (int it=0; it<=TT+2; ++it){
      int ts = it-2;
      if (ts >= 0 && ts < TT){
        int tp = a.summary[b*T1 + ts+1];
        float acc = 0.f;
        #pragma unroll
        for (int i=0;i<6;i++){
          int k = l + 64*i;
          float x = (k < 256) ? a.ctx[((size_t)(ts&1)*BB + b)*256 + k]
                              : a.hn[((size_t)(ts&3)*BB + b)*HH + (k-256)];
          float w = a.Wl[(size_t)tp*384 + k];
          acc += bf2f(f2bf(x)) * bfrnd(w);
        }
        #pragma unroll
        for (int off=32;off>=1;off>>=1) acc += __shfl_xor(acc, off, 64);
        if (l==0) L.cb.tgt[(ts&1)*BB + b] = acc + a.bl[tp];
      }
      int cs = it-3;
      if (cs >= 0 && cs < TT){
        int slot = cs&1;
        const float* pmp = a.pm + (size_t)slot*BB*CGB + b*CGB;
        const float* psp = a.ps + (size_t)slot*BB*CGB + b*CGB;
        float m = -1e30f;
        for (int jb=l; jb<CGB; jb+=64) m = fmaxf(m, pmp[jb]);
        #pragma unroll
        for (int off=32;off>=1;off>>=1) m = fmaxf(m, __shfl_xor(m, off, 64));
        float s = 0.f;
        for (int jb=l; jb<CGB; jb+=64) s += psp[jb]*fexp(pmp[jb]-m);
        #pragma unroll
        for (int off=32;off>=1;off>>=1) s += __shfl_xor(s, off, 64);
        __syncthreads();
        if (l==0){
          float lse = m + log2f_(s)*0.6931472f;
          bool val = slenb > cs+1;
          L.cb.red[b] = val ? (lse - L.cb.tgt[slot*BB+b] + GAMMA*a.covloss[(cs&3)*BB+b]) : 0.f;
        }
        __syncthreads();
        if (tid==0){
          float sum = 0.f;
          #pragma unroll
          for (int b2=0;b2<BB;b2++) sum += L.cb.red[b2];
          L.cb.loss += sum;
        }
      }
      if (it==TT+2 && tid==0) a.out[0] = L.cb.loss*(1.0f/TT);
      gbar(a.bar);
    }
  } else {
    // ================= CG: vocab MFMA GEMM, Wl in registers (lag 2) ========
    int cb = bid-17;
    int lane = tid & 63, wid = tid >> 6;
    int quad = lane >> 4, col = lane & 15;
    uint4 wreg[24];
    float biasv[2];
    bool nOK[2];
    #pragma unroll
    for (int lt=0; lt<2; lt++){
      int lti = lt*8 + wid;
      bool gv = (lti < TPB);
      int g = cb*TPB + (gv ? lti : 0);
      int n = g*16 + col;
      int nc = (n < VV) ? n : (VV-1);
      const float* wr0 = a.Wl + (size_t)nc*384 + quad*8;
      #pragma unroll
      for (int ks=0; ks<12; ks++){
        float4 w0 = *((const float4*)(wr0 + ks*32));
        float4 w1 = *((const float4*)(wr0 + ks*32 + 4));
        wreg[lt*12+ks] = make_uint4(pack2rq(w0.x,w0.y), pack2rq(w0.z,w0.w),
                                    pack2rq(w1.x,w1.y), pack2rq(w1.z,w1.w));
      }
      nOK[lt] = gv && (n < VV);
      biasv[lt] = nOK[lt] ? a.bl[n] : 0.f;
    }
    for (int it=0; it<=TT+2; ++it){
      int s = it-2;
      if (s >= 0 && s < TT){
        for (int f=tid; f<16*384; f+=512){
          int m2 = f/384, k = f - m2*384;
          float v = 0.f;
          if (m2 < 8) v = (k < 256) ? a.ctx[((size_t)(s&1)*BB + m2)*256 + k]
                                    : a.hn[((size_t)(s&3)*BB + m2)*HH + (k-256)];
          L.cg.xs[m2*392 + k] = f2bf(v);
        }
        __syncthreads();
        const unsigned short* ap = L.cg.xs + col*392 + quad*8;
        float mr[4], sr[4];
        #pragma unroll
        for (int r=0;r<4;r++){ mr[r] = -1e30f; sr[r] = 0.f; }
        #pragma unroll
        for (int lt=0; lt<2; lt++){
          cfrag acc; acc.x=0.f; acc.y=0.f; acc.z=0.f; acc.w=0.f;
          #pragma unroll
          for (int ks=0; ks<12; ks++){
            bfrag af = *((const bfrag*)(ap + ks*32));
            bfrag bf = __builtin_bit_cast(bfrag, wreg[lt*12+ks]);
            acc = __builtin_amdgcn_mfma_f32_16x16x32_bf16(af, bf, acc, 0,0,0);
          }
          #pragma unroll
          for (int r=0;r<4;r++){
            int mrow = quad*4 + r;
            float v = (mrow < 8 && nOK[lt]) ? (acc[r]+biasv[lt]) : -1e30f;
            float nm = fmaxf(mr[r], v);
            float ev = (v <= -1e29f) ? 0.f : fexp(v-nm);
            sr[r] = sr[r]*fexp(mr[r]-nm) + ev;
            mr[r] = nm;
          }
        }
        #pragma unroll
        for (int off=1; off<16; off<<=1){
          #pragma unroll
          for (int r=0;r<4;r++){
            float m2 = __shfl_xor(mr[r], off, 64);
            float s2 = __shfl_xor(sr[r], off, 64);
            float nm = fmaxf(mr[r], m2);
            sr[r] = sr[r]*fexp(mr[r]-nm) + s2*fexp(m2-nm);
            mr[r] = nm;
          }
        }
        if (col==0 && quad<2){
          #pragma unroll
          for (int r=0;r<4;r++){
            L.cg.rm[wid*8 + quad*4 + r] = mr[r];
            L.cg.rs[wid*8 + quad*4 + r] = sr[r];
          }
        }
        __syncthreads();
        if (tid < 8){
          float M = -1e30f, S = 0.f;
          #pragma unroll
          for (int w8=0; w8<8; w8++){
            float m2 = L.cg.rm[w8*8+tid], s2 = L.cg.rs[w8*8+tid];
            float nm = fmaxf(M, m2);
            S = S*fexp(M-nm) + s2*fexp(m2-nm);
            M = nm;
          }
          a.pm[(size_t)(s&1)*BB*CGB + tid*CGB + cb] = M;
          a.ps[(size_t)(s&1)*BB*CGB + tid*CGB + cb] = S;
        }
      }
      gbar(a.bar);
    }
  }
}

// ---------------- host ----------------
extern "C" void kernel_launch(void* const* d_in, const int* in_sizes, int n_in,
                              void* d_out, int out_size, void* d_ws, size_t ws_size,
                              hipStream_t stream){
  const int* text      = (const int*)d_in[0];
  const int* tlen      = (const int*)d_in[1];
  const int* summary   = (const int*)d_in[2];
  const int* slen      = (const int*)d_in[3];
  const float* wv      = (const float*)d_in[4];
  const float* Wih_f   = (const float*)d_in[5];
  const float* Whh_f   = (const float*)d_in[6];
  const float* bih_f   = (const float*)d_in[7];
  const float* bhh_f   = (const float*)d_in[8];
  const float* Wih_b   = (const float*)d_in[9];
  const float* Whh_b   = (const float*)d_in[10];
  const float* bih_b   = (const float*)d_in[11];
  const float* bhh_b   = (const float*)d_in[12];
  const float* Wdih    = (const float*)d_in[13];
  const float* Wdhh    = (const float*)d_in[14];
  const float* bdih    = (const float*)d_in[15];
  const float* bdhh    = (const float*)d_in[16];
  const float* W1      = (const float*)d_in[17];
  const float* b1      = (const float*)d_in[18];
  const float* W2      = (const float*)d_in[19];
  const float* Wl      = (const float*)d_in[21];
  const float* bl      = (const float*)d_in[22];

  char* ws = (char*)d_ws;
  size_t off = 0;
  auto alloc = [&](size_t n)->void*{
    off = (off + 255) & ~(size_t)255;
    void* p = ws + off; off += n; return p;
  };

  // ---- decode-persistent region (~4 MB) ----
  unsigned* W1h2   = (unsigned*)alloc((size_t)8192*4);
  unsigned* Wdh2T  = (unsigned*)alloc((size_t)64*512*4);
  float*    Xd     = (float*)alloc((size_t)TT*BB*G4*4);
  unsigned* ts_h   = (unsigned*)alloc((size_t)BB*2*128*256*4);
  unsigned* TS1Th  = (unsigned*)alloc((size_t)BB*64*512*4);
  float* W1c       = (float*)alloc((size_t)128*4);
  float* h0        = (float*)alloc(BB*HH*4);
  float* c0        = (float*)alloc(BB*HH*4);
  float* hn        = (float*)alloc(4*(size_t)BB*HH*4);
  float* ctx       = (float*)alloc(2*(size_t)BB*256*4);
  float* attn      = (float*)alloc(2*(size_t)BB*SS*4);
  float* covloss   = (float*)alloc(4*BB*4);
  float* pm        = (float*)alloc(2*(size_t)BB*CGB*4);
  float* ps        = (float*)alloc(2*(size_t)BB*CGB*4);
  unsigned* bar    = (unsigned*)alloc(256);

  // ---- encoder-transient region ----
  float* emb     = (float*)alloc((size_t)BB*SS*DD*4);
  float* Xf      = (float*)alloc(((size_t)BB*SS*G4 + 8*G4)*4);
  float* Xb      = (float*)alloc(((size_t)BB*SS*G4 + 8*G4)*4);
  float* WihT_f  = (float*)alloc((size_t)256*512*4);
  float* WihT_b  = (float*)alloc((size_t)256*512*4);
  unsigned* W2T_f= (unsigned*)alloc((size_t)64*512*4);
  unsigned* W2T_b= (unsigned*)alloc((size_t)64*512*4);
  float* out_f   = (float*)alloc((size_t)BB*SS*HH*4);
  float* out_r   = (float*)alloc((size_t)BB*SS*HH*4);
  float* W1aT    = (float*)alloc((size_t)256*128*4);
  int*   ridx    = (int*)  alloc((size_t)BB*SS*4);

  k_prep_small<<<1569,256,0,stream>>>(Wih_f,Wih_b,Whh_f,Whh_b,W1,Wdhh,
                                      WihT_f,WihT_b,W2T_f,W2T_b,W1aT,W1c,W1h2,Wdh2T);
  k_xd<<<TT,512,0,stream>>>(summary, wv, Wdih, bdih, bdhh, Xd, bar);
  k_embed<<<BB*SS,64,0,stream>>>(text, tlen, wv, emb, ridx);
  k_xgemm<<<512,256,0,stream>>>(emb, ridx, WihT_f, bih_f, bhh_f, Xf, 0);
  k_xgemm<<<512,256,0,stream>>>(emb, ridx, WihT_b, bih_b, bhh_b, Xb, 1);
  k_encoder<<<dim3(8,2),512,0,stream>>>(Xf,Xb,W2T_f,W2T_b,tlen,out_f,out_r,h0,c0);
  k_post<<<dim3(8,16),256,0,stream>>>(out_f,out_r,ridx,W1aT,ts_h,TS1Th);

  PArgs a;
  a.summary=summary; a.slen=slen;
  a.Xd=Xd; a.TS1Th=TS1Th; a.ts_h=ts_h;
  a.W1h2g=W1h2; a.W1c=W1c; a.W2=W2; a.b1=b1;
  a.Wdh2T=Wdh2T; a.Wl=Wl; a.bl=bl;
  a.h0=h0; a.c0=c0;
  a.hn=hn; a.ctx=ctx; a.attn=attn; a.covloss=covloss;
  a.pm=pm; a.ps=ps; a.bar=bar; a.out=(float*)d_out;

  k_decode<<<NBLK,512,0,stream>>>(a);
}

// Round 6
// 2568.945 us; speedup vs baseline: 3.9328x; 1.2909x over previous
//
#include <hip/hip_runtime.h>
#include <hip/hip_bf16.h>

#define VV 50000
#define DD 256
#define HH 128
#define G4 512
#define BB 8
#define SS 512
#define TT 100
#define T1 101
#define GAMMA 1.0f
#define LOG2E 1.44269504f
#define CGB 224              // GEMM blocks
#define TPB 14               // vocab 16-tiles per GEMM block (224*14*16 = 50176)
#define NBLK (17+CGB)        // 0-7 AB, 8-15 CTX, 16 combine, 17..240 GEMM

__device__ inline float rcpf_(float x){
#if __has_builtin(__builtin_amdgcn_rcpf)
  return __builtin_amdgcn_rcpf(x);
#else
  return 1.0f/x;
#endif
}
__device__ inline float exp2f_(float x){
#if __has_builtin(__builtin_amdgcn_exp2f)
  return __builtin_amdgcn_exp2f(x);
#else
  return exp2f(x);
#endif
}
__device__ inline float log2f_(float x){
#if __has_builtin(__builtin_amdgcn_logf)
  return __builtin_amdgcn_logf(x);
#else
  return log2f(x);
#endif
}
__device__ inline float fexp(float x){ return exp2f_(x*LOG2E); }
__device__ inline float sigf(float x){ return rcpf_(1.f + exp2f_(-x*LOG2E)); }
// tanh = 1 - 2/(e^2x+1): no clamp needed (inf -> 1, 0 -> -1), 5 ops, 2 trans
__device__ inline float tanh_(float x){
  float e = exp2f_(x*(2.0f*LOG2E));
  return 1.0f - 2.0f*rcpf_(e+1.0f);
}
__device__ inline unsigned short f2bf(float x){
  unsigned u = __float_as_uint(x);
  return (unsigned short)((u + 0x7fffu + ((u>>16)&1u)) >> 16);
}
__device__ inline float bf2f(unsigned short s){ return __uint_as_float(((unsigned)s)<<16); }
__device__ inline float bfrnd(float x){
  return __uint_as_float((__float_as_uint(x)+0x8000u)&0xffff0000u);
}
__device__ inline unsigned pack2rq(float a, float b){
#if __has_builtin(__builtin_amdgcn_perm)
  unsigned ua = __float_as_uint(a) + 0x8000u;
  unsigned ub = __float_as_uint(b) + 0x8000u;
  return __builtin_amdgcn_perm(ub, ua, 0x07060302u);
#else
  unsigned ra = (__float_as_uint(a)+0x8000u)>>16;
  unsigned rb = (__float_as_uint(b)+0x8000u)>>16;
  return ra | (rb<<16);
#endif
}

typedef __attribute__((ext_vector_type(2))) _Float16 h2v;
typedef __attribute__((ext_vector_type(8))) short bfrag;
typedef __attribute__((ext_vector_type(4))) float cfrag;

__device__ inline unsigned packh2(float a, float b){
  unsigned short ha = __builtin_bit_cast(unsigned short, (_Float16)a);
  unsigned short hb = __builtin_bit_cast(unsigned short, (_Float16)b);
  return (unsigned)ha | ((unsigned)hb<<16);
}
__device__ inline float fdot2_(unsigned a, unsigned b, float c){
#if __has_builtin(__builtin_amdgcn_fdot2)
  return __builtin_amdgcn_fdot2(__builtin_bit_cast(h2v, a), __builtin_bit_cast(h2v, b), c, false);
#else
  h2v av = __builtin_bit_cast(h2v, a), bv = __builtin_bit_cast(h2v, b);
  return c + (float)av.x*(float)bv.x + (float)av.y*(float)bv.y;
#endif
}
__device__ inline float hlo(unsigned u){ return (float)__builtin_bit_cast(h2v, u).x; }
__device__ inline float hhi(unsigned u){ return (float)__builtin_bit_cast(h2v, u).y; }

// ------ hierarchical device-scope barrier: 8 padded group lines + root ------
// bar layout (dwords): lcnt[g] @ 64*g (g=0..7), gcnt @ 512, gen @ 576
__device__ inline void gbar(unsigned* bar){
  __syncthreads();
  if (threadIdx.x == 0){
    __threadfence();
    int g = blockIdx.x & 7;
    unsigned gsz = (unsigned)((NBLK + 7 - g) >> 3);
    unsigned gen = __hip_atomic_load(bar+576, __ATOMIC_RELAXED, __HIP_MEMORY_SCOPE_AGENT);
    unsigned old = __hip_atomic_fetch_add(bar+64*g, 1u, __ATOMIC_ACQ_REL, __HIP_MEMORY_SCOPE_AGENT);
    if (old == gsz-1u){
      __hip_atomic_store(bar+64*g, 0u, __ATOMIC_RELAXED, __HIP_MEMORY_SCOPE_AGENT);
      unsigned go = __hip_atomic_fetch_add(bar+512, 1u, __ATOMIC_ACQ_REL, __HIP_MEMORY_SCOPE_AGENT);
      if (go == 7u){
        __hip_atomic_store(bar+512, 0u, __ATOMIC_RELAXED, __HIP_MEMORY_SCOPE_AGENT);
        __hip_atomic_fetch_add(bar+576, 1u, __ATOMIC_RELEASE, __HIP_MEMORY_SCOPE_AGENT);
      } else {
        while (__hip_atomic_load(bar+576, __ATOMIC_RELAXED, __HIP_MEMORY_SCOPE_AGENT) == gen)
          __builtin_amdgcn_s_sleep(2);
      }
    } else {
      while (__hip_atomic_load(bar+576, __ATOMIC_RELAXED, __HIP_MEMORY_SCOPE_AGENT) == gen)
        __builtin_amdgcn_s_sleep(2);
    }
    __threadfence();
  }
  __syncthreads();
}

// ---------------- prep: small weight transposes/packs ----------------
__global__ void __launch_bounds__(256) k_prep_small(
    const float* Wih_f, const float* Wih_b, const float* Whh_f, const float* Whh_b,
    const float* W1, const float* Wdhh,
    float* WihT_f, float* WihT_b, unsigned* W2T_f, unsigned* W2T_b,
    float* W1aT, float* W1c, unsigned* W1h2, unsigned* Wdh2T){
  int i = blockIdx.x*256 + threadIdx.x;
  if (i < 131072){ int k = i>>9, j = i&511; WihT_f[i] = Wih_f[j*DD + k]; return; }
  i -= 131072;
  if (i < 131072){ int k = i>>9, j = i&511; WihT_b[i] = Wih_b[j*DD + k]; return; }
  i -= 131072;
  if (i < 32768){ int k2 = i>>9, j = i&511;
    W2T_f[i] = packh2(Whh_f[j*HH + 2*k2], Whh_f[j*HH + 2*k2+1]); return; }
  i -= 32768;
  if (i < 32768){ int k2 = i>>9, j = i&511;
    W2T_b[i] = packh2(Whh_b[j*HH + 2*k2], Whh_b[j*HH + 2*k2+1]); return; }
  i -= 32768;
  if (i < 32768){ int d = i>>7, k = i&127; W1aT[i] = W1[k*385 + d]; return; }
  i -= 32768;
  if (i < 128){ W1c[i] = W1[i*385 + 384]; return; }
  i -= 128;
  if (i < 8192){ int j2 = i>>7, col = i&127;
    W1h2[i] = packh2(W1[col*385 + 256 + 2*j2], W1[col*385 + 256 + 2*j2+1]); return; }
  i -= 8192;
  if (i < 32768){ int q = i>>9, jj = i&511;
    Wdh2T[i] = packh2(Wdhh[jj*HH + 2*q], Wdhh[jj*HH + 2*q+1]); return; }
}

// ---------------- Xd[t][b][j] = Wdih@x + bdih + bdhh ; also zero barrier -----
__global__ void __launch_bounds__(512) k_xd(const int* summary, const float* wv,
    const float* Wdih, const float* bdih, const float* bdhh,
    float* Xd, unsigned* bar){
  __shared__ float xsl[8][256];
  int t = blockIdx.x, tid = threadIdx.x;
  for (int f=tid; f<2048; f+=512){
    int b = f>>8, k = f&255;
    xsl[b][k] = wv[(size_t)summary[b*T1 + t]*DD + k];
  }
  if (blockIdx.x==0){ for (int f=tid; f<1024; f+=512) bar[f] = 0u; }
  __syncthreads();
  int jj = tid;
  float base = bdih[jj] + bdhh[jj];
  const float4* wr = (const float4*)(Wdih + (size_t)jj*DD);
  float acc[8];
  #pragma unroll
  for (int b=0;b<8;b++) acc[b]=0.f;
  for (int q=0;q<64;q++){
    float4 w = wr[q];
    #pragma unroll
    for (int b=0;b<8;b++)
      acc[b] += w.x*xsl[b][4*q] + w.y*xsl[b][4*q+1] + w.z*xsl[b][4*q+2] + w.w*xsl[b][4*q+3];
  }
  #pragma unroll
  for (int b=0;b<8;b++) Xd[((size_t)t*BB + b)*G4 + jj] = base + acc[b];
}

// ---------------- embedding gather + ridx ----------------
__global__ void k_embed(const int* text, const int* tlen, const float* wv,
                        float* emb, int* ridx){
  int blk = blockIdx.x;
  int b = blk>>9, s = blk&511;
  int tok = text[blk];
  const float4* src = (const float4*)(wv + (size_t)tok*DD);
  float4* dst = (float4*)(emb + (size_t)blk*DD);
  dst[threadIdx.x] = src[threadIdx.x];
  if (threadIdx.x==0){ int len = tlen[b]; ridx[blk] = (s < len) ? (len-1-s) : s; }
}

// ---------------- X = emb @ Wih^T + bih + bhh ----------------
__global__ void __launch_bounds__(256) k_xgemm(const float* emb, const int* ridx,
    const float* WihT, const float* bi, const float* bh, float* X, int rev){
  __shared__ float e_l[8][256];
  int tid = threadIdx.x;
  int g0 = blockIdx.x*8;
  int b = g0>>9;
  for (int r=0;r<8;r++){
    int s = (g0+r)&511;
    int src = rev ? ridx[b*SS + s] : s;
    e_l[r][tid] = emb[((size_t)(b*SS+src))*DD + tid];
  }
  __syncthreads();
  int j0 = tid, j1 = tid+256;
  float acc0[8], acc1[8];
  #pragma unroll
  for (int r=0;r<8;r++){ acc0[r]=0.f; acc1[r]=0.f; }
  for (int k=0;k<256;k++){
    float w0 = WihT[k*G4 + j0];
    float w1 = WihT[k*G4 + j1];
    #pragma unroll
    for (int r=0;r<8;r++){ float e = e_l[r][k]; acc0[r] += e*w0; acc1[r] += e*w1; }
  }
  float bb0 = bi[j0]+bh[j0], bb1 = bi[j1]+bh[j1];
  for (int r=0;r<8;r++){
    X[((size_t)(g0+r))*G4 + j0] = acc0[r] + bb0;
    X[((size_t)(g0+r))*G4 + j1] = acc1[r] + bb1;
  }
}

// ------ encoder: register Whh (f16), X preload x8, out buffered x8 ----------
__global__ void __launch_bounds__(512) k_encoder(const float* Xf, const float* Xb,
    const unsigned* W2Tf, const unsigned* W2Tb, const int* tlen,
    float* out_f, float* out_r, float* h0, float* c0){
  __shared__ float g_l[512];
  __shared__ __align__(16) unsigned h2_l[64];
  int tid = threadIdx.x;
  int b = blockIdx.x, dir = blockIdx.y;
  const float* X = dir ? Xb : Xf;
  const unsigned* WT = dir ? W2Tb : W2Tf;
  float* out = dir ? out_r : out_f;
  unsigned w[64];
  #pragma unroll
  for (int k2=0;k2<64;k2++) w[k2] = WT[k2*G4 + tid];
  if (tid < 64) h2_l[tid] = 0u;
  float creg = 0.f, hreg = 0.f;
  int len = tlen[b];
  __syncthreads();
  for (int t0=0;t0<len;t0+=8){
    float x8[8];
    #pragma unroll
    for (int i=0;i<8;i++) x8[i] = X[(size_t)(b*SS+t0+i)*G4 + tid];
    float out8[8];
    #pragma unroll
    for (int i=0;i<8;i++){
      int t = t0+i;
      if (t >= len) break;
      float a0 = x8[i], a1 = 0.f, a2 = 0.f, a3 = 0.f;
      const uint4* h4 = (const uint4*)h2_l;
      #pragma unroll
      for (int q=0;q<16;q++){
        uint4 hv = h4[q];
        a0 = fdot2_(w[4*q+0], hv.x, a0);
        a1 = fdot2_(w[4*q+1], hv.y, a1);
        a2 = fdot2_(w[4*q+2], hv.z, a2);
        a3 = fdot2_(w[4*q+3], hv.w, a3);
      }
      g_l[tid] = (a0+a1)+(a2+a3);
      __syncthreads();
      if (tid < 128){
        float ii = sigf(g_l[tid]);
        float ff = sigf(g_l[128+tid]);
        float gg = tanh_(g_l[256+tid]);
        float oo = sigf(g_l[384+tid]);
        creg = ff*creg + ii*gg;
        float hn = oo*tanh_(creg);
        out8[i] = hn;
        hreg = hn;
        ((_Float16*)h2_l)[tid] = (_Float16)hn;
      }
      __syncthreads();
    }
    if (tid < 128){
      int nend = (len - t0 < 8) ? (len - t0) : 8;
      #pragma unroll 8
      for (int i=0;i<nend;i++) out[((size_t)(b*SS+t0+i))*HH + tid] = out8[i];
    }
  }
  if (dir==0 && tid<128){ h0[b*HH+tid]=hreg; c0[b*HH+tid]=creg; }
  for (int f = tid; f < (SS-len)*HH; f += 512){
    int s = len + (f>>7), j = f&127;
    out[((size_t)(b*SS+s))*HH + j] = 0.f;
  }
}

// ------- post-encoder: ts_h (f16 pairs over s) + TS1Th (f16 pairs over k) ----
__global__ void __launch_bounds__(256) k_post(const float* out_f, const float* out_r,
    const int* ridx, const float* W1aT, unsigned* ts_h, unsigned* TS1Th){
  __shared__ float ts_l[128*33 + 64];   // also reused as pk[k][33]
  int tid = threadIdx.x;
  int b = blockIdx.x, chunk = blockIdx.y;
  int s0 = chunk*32;
  for (int it=0; it<32; ++it){
    int s = s0 + it;
    int d = tid;
    float v;
    if (d < 128) v = out_f[((size_t)(b*SS+s))*HH + d];
    else        v = out_r[((size_t)(b*SS + ridx[b*SS+s]))*HH + (d-128)];
    ts_l[it*256 + d] = v;
  }
  __syncthreads();
  // ts_h[b][half][s2][d]
  for (int f=tid; f<16*256; f+=256){
    int it2 = f>>8, d = f&255;
    unsigned p = packh2(ts_l[(2*it2)*256 + d], ts_l[(2*it2+1)*256 + d]);
    ts_h[((((size_t)b*2 + (s0>>8))*128) + (((s0&255)>>1) + it2))*256 + d] = p;
  }
  int k = tid & 127, half = tid >> 7;
  float acc[16];
  #pragma unroll
  for (int i=0;i<16;i++) acc[i]=0.f;
  for (int d=0;d<256;d++){
    float w = W1aT[d*128 + k];
    #pragma unroll
    for (int i=0;i<16;i++) acc[i] += ts_l[(half*16+i)*256 + d]*w;
  }
  __syncthreads();
  #pragma unroll
  for (int i=0;i<16;i++) ts_l[k*33 + half*16 + i] = acc[i];
  __syncthreads();
  for (int f=tid; f<64*32; f+=256){
    int k2 = f>>5, sl = f&31;
    unsigned p = packh2(ts_l[(2*k2)*33 + sl], ts_l[(2*k2+1)*33 + sl]);
    TS1Th[((size_t)b*64 + k2)*512 + (s0 + sl)] = p;
  }
}

// ---------------- persistent decoder ----------------
struct PArgs {
  const int* summary; const int* slen;
  const float* Xd; const unsigned* TS1Th; const unsigned* ts_h;
  const unsigned* W1h2g; const float* W1c; const float* W2; const float* b1;
  const unsigned* Wdh2T; const float* Wl; const float* bl;
  const float* h0; const float* c0;
  float* hn; float* ctx; float* attn; float* covloss;
  float* pm; float* ps; unsigned* bar; float* out;
};

struct LdsAB {
  unsigned W1h2[8192];
  float gates[512];
  float hnl[128], hml[128], uh[128];
  unsigned hn2[64], hm2[64];
  float wc[128], w2l[128], b1l[128];
  float wredA[8], wredB[8], wredC[8];
};
struct LdsCG { unsigned short xs[16*392]; float rm[64], rs[64]; };
struct LdsCTX { float at[512]; float part[512]; };
struct LdsCB { float tgt[16]; float red[8]; float loss; };
union LdsU { LdsAB ab; LdsCG cg; LdsCTX cx; LdsCB cb; };

__global__ void __launch_bounds__(512,2) k_decode(PArgs a){
  __shared__ LdsU L;
  int bid = blockIdx.x, tid = threadIdx.x;

  if (bid < 8){
    // ================= AB: cell + attention + gates =================
    int b = bid;
    int slenb = a.slen[b];
    if (tid < 128){
      L.ab.wc[tid]  = a.W1c[tid];
      L.ab.w2l[tid] = a.W2[tid];
      L.ab.b1l[tid] = a.b1[tid];
    }
    for (int f=tid; f<8192; f+=512) L.ab.W1h2[f] = a.W1h2g[f];
    unsigned ts2[64];
    #pragma unroll
    for (int k2=0;k2<64;k2++) ts2[k2] = a.TS1Th[((size_t)b*64 + k2)*512 + tid];
    unsigned wdh[64];
    #pragma unroll
    for (int q=0;q<64;q++) wdh[q] = a.Wdh2T[q*512 + tid];
    float creg = 0.f, hmreg = 0.f;
    if (tid < 128){
      creg  = a.c0[b*HH+tid];
      hmreg = a.h0[b*HH+tid];
      L.ab.hml[tid] = hmreg;
    }
    float cv = 0.f;
    __syncthreads();
    if (tid < 64) L.ab.hm2[tid] = packh2(L.ab.hml[2*tid], L.ab.hml[2*tid+1]);
    __syncthreads();
    {
      float g = a.Xd[(size_t)0*BB*G4 + b*G4 + tid];
      #pragma unroll
      for (int q=0;q<64;q++) g = fdot2_(wdh[q], L.ab.hm2[q], g);
      L.ab.gates[tid] = g;
    }
    __syncthreads();

    for (int it=0; it<=TT+2; ++it){
      int t = it;
      if (t < TT){
        int tn = (t+1 < TT) ? t+1 : 0;
        float xdn = a.Xd[(size_t)tn*BB*G4 + b*G4 + tid];   // prefetch
        bool valid = (slenb > t+1);
        if (tid < 128){
          float gi = L.ab.gates[tid];
          float gf = L.ab.gates[128+tid];
          float gg = L.ab.gates[256+tid];
          float go = L.ab.gates[384+tid];
          float ii = sigf(gi), ff = sigf(gf), g2 = tanh_(gg), oo = sigf(go);
          float cn = ff*creg + ii*g2;
          float hv = oo*tanh_(cn);
          if (valid) creg = cn;
          hmreg = valid ? hv : hmreg;
          L.ab.hnl[tid] = hv;
          L.ab.hml[tid] = hmreg;
          a.hn[((size_t)(t&3)*BB + b)*HH + tid] = hv;
        }
        __syncthreads();
        if (tid < 64){
          L.ab.hn2[tid] = packh2(L.ab.hnl[2*tid], L.ab.hnl[2*tid+1]);
          L.ab.hm2[tid] = packh2(L.ab.hml[2*tid], L.ab.hml[2*tid+1]);
        }
        __syncthreads();
        if (tid < 128){
          float acc = L.ab.b1l[tid];
          #pragma unroll
          for (int j2=0;j2<64;j2++) acc = fdot2_(L.ab.W1h2[j2*128+tid], L.ab.hn2[j2], acc);
          L.ab.uh[tid] = acc;
        }
        __syncthreads();
        float sc = 0.f;
        #pragma unroll
        for (int k2=0;k2<64;k2++){
          unsigned tp = ts2[k2];
          float p0 = hlo(tp) + L.ab.uh[2*k2]   + cv*L.ab.wc[2*k2];
          float p1 = hhi(tp) + L.ab.uh[2*k2+1] + cv*L.ab.wc[2*k2+1];
          sc += tanh_(p0)*L.ab.w2l[2*k2];
          sc += tanh_(p1)*L.ab.w2l[2*k2+1];
        }
        int wid = tid>>6;
        float m = sc;
        #pragma unroll
        for (int off=32;off>=1;off>>=1) m = fmaxf(m, __shfl_xor(m, off, 64));
        if ((tid&63)==0) L.ab.wredA[wid] = m;
        __syncthreads();
        m = L.ab.wredA[0];
        #pragma unroll
        for (int w8=1;w8<8;w8++) m = fmaxf(m, L.ab.wredA[w8]);
        float e = fexp(sc - m);
        float es = e;
        #pragma unroll
        for (int off=32;off>=1;off>>=1) es += __shfl_xor(es, off, 64);
        if ((tid&63)==0) L.ab.wredB[wid] = es;
        __syncthreads();
        float ssum = 0.f;
        #pragma unroll
        for (int w8=0;w8<8;w8++) ssum += L.ab.wredB[w8];
        float at = e * rcpf_(ssum);
        a.attn[((size_t)(t&1)*BB + b)*SS + tid] = at;
        float cl = fminf(cv, at);
        #pragma unroll
        for (int off=32;off>=1;off>>=1) cl += __shfl_xor(cl, off, 64);
        if ((tid&63)==0) L.ab.wredC[wid] = cl;
        __syncthreads();
        if (tid==0){
          float cs = 0.f;
          #pragma unroll
          for (int w8=0;w8<8;w8++) cs += L.ab.wredC[w8];
          a.covloss[(t&3)*BB + b] = cs;
        }
        if (valid) cv += at;
        if (t+1 < TT){
          float g = xdn;
          #pragma unroll
          for (int q=0;q<64;q++) g = fdot2_(wdh[q], L.ab.hm2[q], g);
          __syncthreads();
          L.ab.gates[tid] = g;
        }
      }
      gbar(a.bar);
    }
  } else if (bid < 16){
    // ================= CTX: context = attn @ ts (lag 1) =================
    int b = bid-8;
    int d = tid & 255, half = tid >> 8;
    unsigned tsr[128];
    #pragma unroll
    for (int s2=0;s2<128;s2++)
      tsr[s2] = a.ts_h[((((size_t)b*2 + half)*128) + s2)*256 + d];
    for (int it=0; it<=TT+2; ++it){
      int s = it-1;
      if (s >= 0 && s < TT){
        L.cx.at[tid] = a.attn[((size_t)(s&1)*BB + b)*SS + tid];
        __syncthreads();
        float acc = 0.f;
        const float* ap = L.cx.at + half*256;
        #pragma unroll
        for (int s2=0;s2<128;s2++){
          unsigned tp = tsr[s2];
          acc += hlo(tp)*ap[2*s2] + hhi(tp)*ap[2*s2+1];
        }
        L.cx.part[tid] = acc;
        __syncthreads();
        if (tid < 256)
          a.ctx[((size_t)(s&1)*BB + b)*256 + tid] = L.cx.part[tid] + L.cx.part[256+tid];
      }
      gbar(a.bar);
    }
  } else if (bid == 16){
    // ================= CB: target logit (lag 2) + LSE/loss (lag 3) =========
    int b = tid >> 6, l = tid & 63;
    int slenb = a.slen[b];
    if (tid == 0) L.cb.loss = 0.f;
    __syncthreads();
    for (int it=0; it<=TT+2; ++it){
      int ts = it-2;
      if (ts >= 0 && ts < TT){
        int tp = a.summary[b*T1 + ts+1];
        float acc = 0.f;
        #pragma unroll
        for (int i=0;i<6;i++){
          int k = l + 64*i;
          float x = (k < 256) ? a.ctx[((size_t)(ts&1)*BB + b)*256 + k]
                              : a.hn[((size_t)(ts&3)*BB + b)*HH + (k-256)];
          float w = a.Wl[(size_t)tp*384 + k];
          acc += bf2f(f2bf(x)) * bfrnd(w);
        }
        #pragma unroll
        for (int off=32;off>=1;off>>=1) acc += __shfl_xor(acc, off, 64);
        if (l==0) L.cb.tgt[(ts&1)*BB + b] = acc + a.bl[tp];
      }
      int cs = it-3;
      if (cs >= 0 && cs < TT){
        int slot = cs&1;
        const float* pmp = a.pm + (size_t)slot*BB*CGB + b*CGB;
        const float* psp = a.ps + (size_t)slot*BB*CGB + b*CGB;
        float m = -1e30f;
        for (int jb=l; jb<CGB; jb+=64) m = fmaxf(m, pmp[jb]);
        #pragma unroll
        for (int off=32;off>=1;off>>=1) m = fmaxf(m, __shfl_xor(m, off, 64));
        float s = 0.f;
        for (int jb=l; jb<CGB; jb+=64) s += psp[jb]*fexp(pmp[jb]-m);
        #pragma unroll
        for (int off=32;off>=1;off>>=1) s += __shfl_xor(s, off, 64);
        __syncthreads();
        if (l==0){
          float lse = m + log2f_(s)*0.6931472f;
          bool val = slenb > cs+1;
          L.cb.red[b] = val ? (lse - L.cb.tgt[slot*BB+b] + GAMMA*a.covloss[(cs&3)*BB+b]) : 0.f;
        }
        __syncthreads();
        if (tid==0){
          float sum = 0.f;
          #pragma unroll
          for (int b2=0;b2<BB;b2++) sum += L.cb.red[b2];
          L.cb.loss += sum;
        }
      }
      if (it==TT+2 && tid==0) a.out[0] = L.cb.loss*(1.0f/TT);
      gbar(a.bar);
    }
  } else {
    // ================= CG: vocab MFMA GEMM, Wl in registers (lag 2) ========
    int cb = bid-17;
    int lane = tid & 63, wid = tid >> 6;
    int quad = lane >> 4, col = lane & 15;
    uint4 wreg[24];
    float biasv[2];
    bool nOK[2];
    #pragma unroll
    for (int lt=0; lt<2; lt++){
      int lti = lt*8 + wid;
      bool gv = (lti < TPB);
      int g = cb*TPB + (gv ? lti : 0);
      int n = g*16 + col;
      int nc = (n < VV) ? n : (VV-1);
      const float* wr0 = a.Wl + (size_t)nc*384 + quad*8;
      #pragma unroll
      for (int ks=0; ks<12; ks++){
        float4 w0 = *((const float4*)(wr0 + ks*32));
        float4 w1 = *((const float4*)(wr0 + ks*32 + 4));
        wreg[lt*12+ks] = make_uint4(pack2rq(w0.x,w0.y), pack2rq(w0.z,w0.w),
                                    pack2rq(w1.x,w1.y), pack2rq(w1.z,w1.w));
      }
      nOK[lt] = gv && (n < VV);
      biasv[lt] = nOK[lt] ? a.bl[n] : 0.f;
    }
    for (int it=0; it<=TT+2; ++it){
      int s = it-2;
      if (s >= 0 && s < TT){
        for (int f=tid; f<16*384; f+=512){
          int m2 = f/384, k = f - m2*384;
          float v = 0.f;
          if (m2 < 8) v = (k < 256) ? a.ctx[((size_t)(s&1)*BB + m2)*256 + k]
                                    : a.hn[((size_t)(s&3)*BB + m2)*HH + (k-256)];
          L.cg.xs[m2*392 + k] = f2bf(v);
        }
        __syncthreads();
        const unsigned short* ap = L.cg.xs + col*392 + quad*8;
        float mr[4], sr[4];
        #pragma unroll
        for (int r=0;r<4;r++){ mr[r] = -1e30f; sr[r] = 0.f; }
        #pragma unroll
        for (int lt=0; lt<2; lt++){
          cfrag acc; acc.x=0.f; acc.y=0.f; acc.z=0.f; acc.w=0.f;
          #pragma unroll
          for (int ks=0; ks<12; ks++){
            bfrag af = *((const bfrag*)(ap + ks*32));
            bfrag bf = __builtin_bit_cast(bfrag, wreg[lt*12+ks]);
            acc = __builtin_amdgcn_mfma_f32_16x16x32_bf16(af, bf, acc, 0,0,0);
          }
          #pragma unroll
          for (int r=0;r<4;r++){
            int mrow = quad*4 + r;
            float v = (mrow < 8 && nOK[lt]) ? (acc[r]+biasv[lt]) : -1e30f;
            float nm = fmaxf(mr[r], v);
            float ev = (v <= -1e29f) ? 0.f : fexp(v-nm);
            sr[r] = sr[r]*fexp(mr[r]-nm) + ev;
            mr[r] = nm;
          }
        }
        #pragma unroll
        for (int off=1; off<16; off<<=1){
          #pragma unroll
          for (int r=0;r<4;r++){
            float m2 = __shfl_xor(mr[r], off, 64);
            float s2 = __shfl_xor(sr[r], off, 64);
            float nm = fmaxf(mr[r], m2);
            sr[r] = sr[r]*fexp(mr[r]-nm) + s2*fexp(m2-nm);
            mr[r] = nm;
          }
        }
        if (col==0 && quad<2){
          #pragma unroll
          for (int r=0;r<4;r++){
            L.cg.rm[wid*8 + quad*4 + r] = mr[r];
            L.cg.rs[wid*8 + quad*4 + r] = sr[r];
          }
        }
        __syncthreads();
        if (tid < 8){
          float M = -1e30f, S = 0.f;
          #pragma unroll
          for (int w8=0; w8<8; w8++){
            float m2 = L.cg.rm[w8*8+tid], s2 = L.cg.rs[w8*8+tid];
            float nm = fmaxf(M, m2);
            S = S*fexp(M-nm) + s2*fexp(m2-nm);
            M = nm;
          }
          a.pm[(size_t)(s&1)*BB*CGB + tid*CGB + cb] = M;
          a.ps[(size_t)(s&1)*BB*CGB + tid*CGB + cb] = S;
        }
      }
      gbar(a.bar);
    }
  }
}

// ---------------- host ----------------
extern "C" void kernel_launch(void* const* d_in, const int* in_sizes, int n_in,
                              void* d_out, int out_size, void* d_ws, size_t ws_size,
                              hipStream_t stream){
  const int* text      = (const int*)d_in[0];
  const int* tlen      = (const int*)d_in[1];
  const int* summary   = (const int*)d_in[2];
  const int* slen      = (const int*)d_in[3];
  const float* wv      = (const float*)d_in[4];
  const float* Wih_f   = (const float*)d_in[5];
  const float* Whh_f   = (const float*)d_in[6];
  const float* bih_f   = (const float*)d_in[7];
  const float* bhh_f   = (const float*)d_in[8];
  const float* Wih_b   = (const float*)d_in[9];
  const float* Whh_b   = (const float*)d_in[10];
  const float* bih_b   = (const float*)d_in[11];
  const float* bhh_b   = (const float*)d_in[12];
  const float* Wdih    = (const float*)d_in[13];
  const float* Wdhh    = (const float*)d_in[14];
  const float* bdih    = (const float*)d_in[15];
  const float* bdhh    = (const float*)d_in[16];
  const float* W1      = (const float*)d_in[17];
  const float* b1      = (const float*)d_in[18];
  const float* W2      = (const float*)d_in[19];
  const float* Wl      = (const float*)d_in[21];
  const float* bl      = (const float*)d_in[22];

  char* ws = (char*)d_ws;
  size_t off = 0;
  auto alloc = [&](size_t n)->void*{
    off = (off + 255) & ~(size_t)255;
    void* p = ws + off; off += n; return p;
  };

  // ---- decode-persistent region (~4 MB) ----
  unsigned* W1h2   = (unsigned*)alloc((size_t)8192*4);
  unsigned* Wdh2T  = (unsigned*)alloc((size_t)64*512*4);
  float*    Xd     = (float*)alloc((size_t)TT*BB*G4*4);
  unsigned* ts_h   = (unsigned*)alloc((size_t)BB*2*128*256*4);
  unsigned* TS1Th  = (unsigned*)alloc((size_t)BB*64*512*4);
  float* W1c       = (float*)alloc((size_t)128*4);
  float* h0        = (float*)alloc(BB*HH*4);
  float* c0        = (float*)alloc(BB*HH*4);
  float* hn        = (float*)alloc(4*(size_t)BB*HH*4);
  float* ctx       = (float*)alloc(2*(size_t)BB*256*4);
  float* attn      = (float*)alloc(2*(size_t)BB*SS*4);
  float* covloss   = (float*)alloc(4*BB*4);
  float* pm        = (float*)alloc(2*(size_t)BB*CGB*4);
  float* ps        = (float*)alloc(2*(size_t)BB*CGB*4);
  unsigned* bar    = (unsigned*)alloc(4096);

  // ---- encoder-transient region ----
  float* emb     = (float*)alloc((size_t)BB*SS*DD*4);
  float* Xf      = (float*)alloc(((size_t)BB*SS*G4 + 8*G4)*4);
  float* Xb      = (float*)alloc(((size_t)BB*SS*G4 + 8*G4)*4);
  float* WihT_f  = (float*)alloc((size_t)256*512*4);
  float* WihT_b  = (float*)alloc((size_t)256*512*4);
  unsigned* W2T_f= (unsigned*)alloc((size_t)64*512*4);
  unsigned* W2T_b= (unsigned*)alloc((size_t)64*512*4);
  float* out_f   = (float*)alloc((size_t)BB*SS*HH*4);
  float* out_r   = (float*)alloc((size_t)BB*SS*HH*4);
  float* W1aT    = (float*)alloc((size_t)256*128*4);
  int*   ridx    = (int*)  alloc((size_t)BB*SS*4);

  k_prep_small<<<1569,256,0,stream>>>(Wih_f,Wih_b,Whh_f,Whh_b,W1,Wdhh,
                                      WihT_f,WihT_b,W2T_f,W2T_b,W1aT,W1c,W1h2,Wdh2T);
  k_xd<<<TT,512,0,stream>>>(summary, wv, Wdih, bdih, bdhh, Xd, bar);
  k_embed<<<BB*SS,64,0,stream>>>(text, tlen, wv, emb, ridx);
  k_xgemm<<<512,256,0,stream>>>(emb, ridx, WihT_f, bih_f, bhh_f, Xf, 0);
  k_xgemm<<<512,256,0,stream>>>(emb, ridx, WihT_b, bih_b, bhh_b, Xb, 1);
  k_encoder<<<dim3(8,2),512,0,stream>>>(Xf,Xb,W2T_f,W2T_b,tlen,out_f,out_r,h0,c0);
  k_post<<<dim3(8,16),256,0,stream>>>(out_f,out_r,ridx,W1aT,ts_h,TS1Th);

  PArgs a;
  a.summary=summary; a.slen=slen;
  a.Xd=Xd; a.TS1Th=TS1Th; a.ts_h=ts_h;
  a.W1h2g=W1h2; a.W1c=W1c; a.W2=W2; a.b1=b1;
  a.Wdh2T=Wdh2T; a.Wl=Wl; a.bl=bl;
  a.h0=h0; a.c0=c0;
  a.hn=hn; a.ctx=ctx; a.attn=attn; a.covloss=covloss;
  a.pm=pm; a.ps=ps; a.bar=bar; a.out=(float*)d_out;

  k_decode<<<NBLK,512,0,stream>>>(a);
}